// Round 4
// baseline (908.808 us; speedup 1.0000x reference)
//
#include <hip/hip_runtime.h>
#include <math.h>

constexpr int Fdim = 256;
constexpr int Hdim = 256;
constexpr int Kc   = 16;

constexpr int RSTRIDE = 32;
constexpr int NRED    = 34;   // 0..15 nl, 16..31 cluster_sizes, 32 con, 33 trace

typedef __attribute__((ext_vector_type(8))) short s8v;   // 8 bf16 (4 VGPRs)
typedef __attribute__((ext_vector_type(4))) float f4v;   // 4 fp32 acc

__device__ __forceinline__ float selu1(float x){
    const float scale = 1.0507009873554805f;
    const float alpha = 1.6732632423543772f;
    return scale * (x > 0.f ? x : alpha * expm1f(x));
}

__device__ __forceinline__ ushort f2bf(float x){
    union { float f; unsigned u; } c; c.f = x;
    unsigned r = c.u + 0x7fffu + ((c.u >> 16) & 1u);   // RNE
    return (ushort)(r >> 16);
}

__device__ __forceinline__ float bf2f(ushort b){
    union { unsigned u; float f; } c; c.u = ((unsigned)b) << 16;
    return c.f;
}

// ---------------- CSR build ----------------
__global__ void hist_kernel(const int* __restrict__ src, const int* __restrict__ dst,
                            int* __restrict__ scnt, int* __restrict__ dcnt, int E){
    int i = blockIdx.x * blockDim.x + threadIdx.x;
    if (i < E){
        atomicAdd(&scnt[src[i]], 1);
        atomicAdd(&dcnt[dst[i]], 1);
    }
}

__global__ void scan_kernel(const int* __restrict__ cnt, int* __restrict__ roff, int n){
    __shared__ int sums[1024];
    int t = threadIdx.x;
    int chunk = (n + 1023) / 1024;
    int lo = t * chunk;
    int hi = min(lo + chunk, n);
    int s = 0;
    for (int i = lo; i < hi; ++i) s += cnt[i];
    sums[t] = s;
    __syncthreads();
    for (int off = 1; off < 1024; off <<= 1){
        int v = (t >= off) ? sums[t - off] : 0;
        __syncthreads();
        sums[t] += v;
        __syncthreads();
    }
    int run = sums[t] - s;  // exclusive prefix
    for (int i = lo; i < hi; ++i){ roff[i] = run; run += cnt[i]; }
    if (t == 1023) roff[n] = sums[1023];
}

__global__ void scatter_kernel(const int* __restrict__ src, const int* __restrict__ dst,
                               const float* __restrict__ w, const int* __restrict__ roff,
                               int* __restrict__ cur, int* __restrict__ cdst,
                               float* __restrict__ cw, int E){
    int i = blockIdx.x * blockDim.x + threadIdx.x;
    if (i < E){
        int s = src[i];
        int p = roff[s] + atomicAdd(&cur[s], 1);
        cdst[p] = dst[i];
        cw[p]   = w[i];
    }
}

// ---------------- W1 transpose-cast: Wt[n][k] = bf16(W1[k][n]) ----------------
__global__ void castw_kernel(const float* __restrict__ W, ushort* __restrict__ Wt){
    __shared__ float t[16][17];
    int tx = threadIdx.x, ty = threadIdx.y;
    int k  = blockIdx.y * 16 + ty;
    int nn = blockIdx.x * 16 + tx;
    t[ty][tx] = W[k * 256 + nn];
    __syncthreads();
    int n2 = blockIdx.x * 16 + ty;
    int k2 = blockIdx.y * 16 + tx;
    Wt[n2 * 256 + k2] = f2bf(t[tx][ty]);
}

// ---------------- MFMA bf16 GEMM: chunked C layout [8][N][32] = A_f32 @ W ----------
// block: 256 thr (4 waves), BM=128, BN=128. grid = (2, ceil(M/128)).
__global__ __launch_bounds__(256, 2) void gemm_xw_kernel(
        const float* __restrict__ A, const ushort* __restrict__ Bt,
        ushort* __restrict__ C, int M){
    __shared__ ushort blds[32768];
    int tid = threadIdx.x;
    int n0  = blockIdx.x * 128;
    int bm  = blockIdx.y * 128;

    #pragma unroll
    for (int j = 0; j < 16; ++j){
        int c  = j * 256 + tid;
        int nl = c >> 5, kc = c & 31;
        uint4 v = *reinterpret_cast<const uint4*>(Bt + (((size_t)(n0 + nl)) << 8) + (kc << 3));
        unsigned boff = (unsigned)(((nl << 9) + (kc << 4)) ^ ((nl & 7) << 4));
        *reinterpret_cast<uint4*>(reinterpret_cast<char*>(blds) + boff) = v;
    }
    __syncthreads();

    int w = tid >> 6, l = tid & 63;
    int lr = l & 15, lk = l >> 4;

    f4v acc[2][8];
    #pragma unroll
    for (int m = 0; m < 2; ++m)
        #pragma unroll
        for (int t = 0; t < 8; ++t)
            acc[m][t] = (f4v){0.f, 0.f, 0.f, 0.f};

    int r0 = bm + w * 32 + lr;
    int r1 = r0 + 16;
    int rc0 = min(r0, M - 1), rc1 = min(r1, M - 1);
    const float* a0 = A + (size_t)rc0 * 256 + lk * 8;
    const float* a1 = A + (size_t)rc1 * 256 + lk * 8;

    for (int ks = 0; ks < 8; ++ks){
        s8v af0, af1;
        {
            float4 f0 = *reinterpret_cast<const float4*>(a0 + ks * 32);
            float4 f1 = *reinterpret_cast<const float4*>(a0 + ks * 32 + 4);
            af0[0] = (short)f2bf(f0.x); af0[1] = (short)f2bf(f0.y);
            af0[2] = (short)f2bf(f0.z); af0[3] = (short)f2bf(f0.w);
            af0[4] = (short)f2bf(f1.x); af0[5] = (short)f2bf(f1.y);
            af0[6] = (short)f2bf(f1.z); af0[7] = (short)f2bf(f1.w);
        }
        {
            float4 f0 = *reinterpret_cast<const float4*>(a1 + ks * 32);
            float4 f1 = *reinterpret_cast<const float4*>(a1 + ks * 32 + 4);
            af1[0] = (short)f2bf(f0.x); af1[1] = (short)f2bf(f0.y);
            af1[2] = (short)f2bf(f0.z); af1[3] = (short)f2bf(f0.w);
            af1[4] = (short)f2bf(f1.x); af1[5] = (short)f2bf(f1.y);
            af1[6] = (short)f2bf(f1.z); af1[7] = (short)f2bf(f1.w);
        }
        #pragma unroll
        for (int t = 0; t < 8; ++t){
            int nl = t * 16 + lr;
            unsigned boff = (unsigned)(((nl << 9) + ((ks * 4 + lk) << 4)) ^ ((nl & 7) << 4));
            s8v bf = *reinterpret_cast<const s8v*>(reinterpret_cast<const char*>(blds) + boff);
            acc[0][t] = __builtin_amdgcn_mfma_f32_16x16x32_bf16(af0, bf, acc[0][t], 0, 0, 0);
            acc[1][t] = __builtin_amdgcn_mfma_f32_16x16x32_bf16(af1, bf, acc[1][t], 0, 0, 0);
        }
    }

    // chunked store: col -> chunk=col>>5, within=col&31; addr = chunk*(M32) + row*32 + within
    size_t cstride = (size_t)M * 32;
    #pragma unroll
    for (int m = 0; m < 2; ++m){
        #pragma unroll
        for (int t = 0; t < 8; ++t){
            int col = n0 + t * 16 + lr;
            size_t cbase = (size_t)(col >> 5) * cstride + (size_t)(col & 31);
            #pragma unroll
            for (int j = 0; j < 4; ++j){
                int row = bm + w * 32 + m * 16 + lk * 4 + j;
                if (row < M) C[cbase + (size_t)row * 32] = f2bf(acc[m][t][j]);
            }
        }
    }
}

// ---------------- chunked SPMM over H: chunk = bid&7 (XCD-affine), 1 wave/row ----------
// lanes: slot = lane>>4 (4 edges in flight), cl = lane&15 (2 cols each -> 32 cols)
__global__ __launch_bounds__(256) void spmm_h_chunk_kernel(
        const ushort* __restrict__ XWc,   // [8][n][32] bf16
        const int* __restrict__ roff, const int* __restrict__ cdst,
        const float* __restrict__ cw, const float* __restrict__ b1,
        ushort* __restrict__ G, int n){
    int tid  = threadIdx.x;
    int wid  = tid >> 6, lane = tid & 63;
    int chunk = blockIdx.x & 7;
    int r = (blockIdx.x >> 3) * 4 + wid;
    if (r >= n) return;
    int slot = lane >> 4;
    int cl   = lane & 15;
    const ushort* tab = XWc + (size_t)chunk * ((size_t)n * 32);
    int e0 = roff[r], e1 = roff[r + 1];
    float ax = 0.f, ay = 0.f;
    for (int eb = e0; eb < e1; eb += 4){
        int e  = eb + slot;
        int ec = min(e, e1 - 1);
        int d  = __builtin_nontemporal_load(cdst + ec);
        float w = __builtin_nontemporal_load(cw + ec);
        if (e >= e1) w = 0.f;
        unsigned v = *reinterpret_cast<const unsigned*>(tab + ((size_t)d << 5) + (cl << 1));
        ax = fmaf(w, bf2f((ushort)(v & 0xffffu)), ax);
        ay = fmaf(w, bf2f((ushort)(v >> 16)), ay);
    }
    ax += __shfl_xor(ax, 16); ax += __shfl_xor(ax, 32);
    ay += __shfl_xor(ay, 16); ay += __shfl_xor(ay, 32);
    if (slot == 0){
        int col = (chunk << 5) + (cl << 1);
        float2 bb = *reinterpret_cast<const float2*>(b1 + col);
        unsigned o = (unsigned)f2bf(selu1(ax + bb.x))
                   | ((unsigned)f2bf(selu1(ay + bb.y)) << 16);
        __builtin_nontemporal_store(o,
            reinterpret_cast<unsigned*>(G + (size_t)r * Hdim + col));
    }
}

// ---------------- GS = G_bf16 @ Wk  [N,256]x[256,16] (one wave per row) ----------------
__global__ __launch_bounds__(256) void gemm_k_kernel(const ushort* __restrict__ G,
        const float* __restrict__ Wk, float* __restrict__ GS, int n){
    __shared__ float ws[Hdim][Kc];  // 16 KB
    int t = threadIdx.x;
    {
        const float4* sp = reinterpret_cast<const float4*>(Wk + (size_t)t * Kc);
        float4* dp = reinterpret_cast<float4*>(&ws[t][0]);
        dp[0] = sp[0]; dp[1] = sp[1]; dp[2] = sp[2]; dp[3] = sp[3];
    }
    __syncthreads();
    int wid = t >> 6, lane = t & 63;
    int q = lane >> 4, k = lane & 15;
    int r = blockIdx.x * 4 + wid;
    if (r >= n) return;
    const ushort* grow = G + (size_t)r * Hdim;
    float acc = 0.f;
    #pragma unroll 8
    for (int i = 0; i < 64; ++i){
        int h = i * 4 + q;
        acc = fmaf(bf2f(grow[h]), ws[h][k], acc);
    }
    acc += __shfl_xor(acc, 16);
    acc += __shfl_xor(acc, 32);
    if (lane < 16) GS[(size_t)r * Kc + k] = acc;
}

// ---------------- SPMM over K=16 + bias + selu + softmax ----------------
__global__ __launch_bounds__(256) void spmm_k_softmax(const float* __restrict__ GS,
        const int* __restrict__ roff, const int* __restrict__ cdst,
        const float* __restrict__ cw, const float* __restrict__ bsv,
        float* __restrict__ assign, int n){
    int t = threadIdx.x;
    int lane = t & 63;
    int grp = lane >> 4;
    int j = lane & 15;
    int wid = t >> 6;
    int r = blockIdx.x * 16 + wid * 4 + grp;
    if (r >= n) return;
    int e0 = roff[r], e1 = roff[r + 1];
    float acc = 0.f;
    for (int e = e0; e < e1; ++e){
        int d = cdst[e];
        float w = cw[e];
        acc = fmaf(w, GS[(size_t)d * Kc + j], acc);
    }
    float x = selu1(acc + bsv[j]);
    float m = x;
    #pragma unroll
    for (int off = 8; off >= 1; off >>= 1) m = fmaxf(m, __shfl_xor(m, off));
    float ev = expf(x - m);
    float s = ev;
    #pragma unroll
    for (int off = 8; off >= 1; off >>= 1) s += __shfl_xor(s, off);
    assign[(size_t)r * Kc + j] = ev / s;
}

// ---------------- per-node reductions ----------------
__global__ __launch_bounds__(256) void node_stats_kernel(const float* __restrict__ as_,
        const float* __restrict__ at_, const int* __restrict__ deg,
        float* __restrict__ red, int n){
    int tid    = blockIdx.x * blockDim.x + threadIdx.x;
    int stride = gridDim.x * blockDim.x;
    float nl[16] = {}, cs[16] = {};
    float con = 0.f;
    for (int i = tid; i < n; i += stride){
        float a[16], b[16];
        const float4* pa = reinterpret_cast<const float4*>(as_ + (size_t)i * 16);
        const float4* pb = reinterpret_cast<const float4*>(at_ + (size_t)i * 16);
        #pragma unroll
        for (int q = 0; q < 4; ++q){
            float4 va = pa[q]; float4 vb = pb[q];
            a[q*4+0]=va.x; a[q*4+1]=va.y; a[q*4+2]=va.z; a[q*4+3]=va.w;
            b[q*4+0]=vb.x; b[q*4+1]=vb.y; b[q*4+2]=vb.z; b[q*4+3]=vb.w;
        }
        float d = (float)deg[i];
        float na = 0.f, nb = 0.f, dot = 0.f;
        #pragma unroll
        for (int k = 0; k < 16; ++k){
            na  = fmaf(a[k], a[k], na);
            nb  = fmaf(b[k], b[k], nb);
            dot = fmaf(a[k], b[k], dot);
            nl[k] += a[k] * d;
            cs[k] += a[k];
        }
        na = fmaxf(sqrtf(na), 1e-12f);
        nb = fmaxf(sqrtf(nb), 1e-12f);
        con += 2.f - 2.f * dot / (na * nb);
    }
    #pragma unroll
    for (int k = 0; k < 16; ++k){
        #pragma unroll
        for (int off = 1; off < 64; off <<= 1){
            nl[k] += __shfl_xor(nl[k], off);
            cs[k] += __shfl_xor(cs[k], off);
        }
    }
    #pragma unroll
    for (int off = 1; off < 64; off <<= 1) con += __shfl_xor(con, off);

    __shared__ float part[4][40];
    int wid = threadIdx.x >> 6, lane = threadIdx.x & 63;
    if (lane == 0){
        #pragma unroll
        for (int k = 0; k < 16; ++k){
            part[wid][k]      = nl[k];
            part[wid][16 + k] = cs[k];
        }
        part[wid][32] = con;
    }
    __syncthreads();
    int t = threadIdx.x;
    if (t < 33){
        float s = part[0][t] + part[1][t] + part[2][t] + part[3][t];
        atomicAdd(&red[t * RSTRIDE], s);
    }
}

// ---------------- per-edge trace ----------------
__global__ __launch_bounds__(256) void edge_trace_kernel(const int* __restrict__ src,
        const int* __restrict__ dst, const float* __restrict__ as_,
        float* __restrict__ red, int E){
    int tid    = blockIdx.x * blockDim.x + threadIdx.x;
    int stride = gridDim.x * blockDim.x;
    float dot = 0.f;
    for (int i = tid; i < E; i += stride){
        const float4* pa = reinterpret_cast<const float4*>(as_ + (size_t)src[i] * 16);
        const float4* pb = reinterpret_cast<const float4*>(as_ + (size_t)dst[i] * 16);
        #pragma unroll
        for (int q = 0; q < 4; ++q){
            float4 va = pa[q]; float4 vb = pb[q];
            dot = fmaf(va.x, vb.x, dot); dot = fmaf(va.y, vb.y, dot);
            dot = fmaf(va.z, vb.z, dot); dot = fmaf(va.w, vb.w, dot);
        }
    }
    #pragma unroll
    for (int off = 1; off < 64; off <<= 1) dot += __shfl_xor(dot, off);
    __shared__ float part[4];
    int wid = threadIdx.x >> 6, lane = threadIdx.x & 63;
    if (lane == 0) part[wid] = dot;
    __syncthreads();
    if (threadIdx.x == 0)
        atomicAdd(&red[33 * RSTRIDE], part[0] + part[1] + part[2] + part[3]);
}

// ---------------- finalize ----------------
__global__ void finalize_kernel(const float* __restrict__ red, float* __restrict__ out,
                                int n, int E){
    float trace = red[33 * RSTRIDE];
    float nl2 = 0.f, cs2 = 0.f;
    #pragma unroll
    for (int k = 0; k < 16; ++k){
        nl2 = fmaf(red[k * RSTRIDE],        red[k * RSTRIDE],        nl2);
        cs2 = fmaf(red[(16 + k) * RSTRIDE], red[(16 + k) * RSTRIDE], cs2);
    }
    float twoE = 2.f * (float)E;
    float spectral = -(trace - nl2 / twoE) / twoE;
    float cluster  = sqrtf(cs2) / (float)n * 4.f - 1.f;
    float con      = red[32 * RSTRIDE] / (float)n;
    out[0] = spectral + cluster + con;
}

extern "C" void kernel_launch(void* const* d_in, const int* in_sizes, int n_in,
                              void* d_out, int out_size, void* d_ws, size_t ws_size,
                              hipStream_t stream){
    const int*   esrc = (const int*)d_in[0];
    const int*   edst = (const int*)d_in[1];
    const float* ew   = (const float*)d_in[2];
    const float* feat = (const float*)d_in[3];
    const float* faug = (const float*)d_in[4];
    const float* W1   = (const float*)d_in[5];
    const float* b1   = (const float*)d_in[6];
    const float* Wsm  = (const float*)d_in[7];
    const float* bsv  = (const float*)d_in[8];
    const float* Wtm  = (const float*)d_in[9];
    const float* btv  = (const float*)d_in[10];
    int E = in_sizes[0];
    int N = in_sizes[3] / Fdim;

    char* ws = (char*)d_ws;
    size_t off = 0;
    auto alloc = [&](size_t bytes) -> char* {
        char* p = ws + off;
        off = (off + bytes + 255) & ~(size_t)255;
        return p;
    };
    ushort* XWs   = (ushort*)alloc((size_t)N * Hdim * 2);   // chunked [8][N][32]
    ushort* XWt   = (ushort*)alloc((size_t)N * Hdim * 2);   // chunked [8][N][32]
    ushort* Gs    = (ushort*)alloc((size_t)N * Hdim * 2);
    ushort* Gt    = (ushort*)alloc((size_t)N * Hdim * 2);
    float*  GS_s  = (float*)alloc((size_t)N * Kc * 4);
    float*  GS_t  = (float*)alloc((size_t)N * Kc * 4);
    float*  ASG_S = (float*)alloc((size_t)N * Kc * 4);
    float*  ASG_T = (float*)alloc((size_t)N * Kc * 4);
    ushort* WT    = (ushort*)alloc((size_t)256 * 256 * 2);
    int*    ROFF  = (int*)alloc((size_t)(N + 1) * 4);
    int*    CNT   = (int*)alloc((size_t)N * 4);
    int*    CUR   = (int*)alloc((size_t)N * 4);
    int*    DEG   = (int*)alloc((size_t)N * 4);
    int*    CDST  = (int*)alloc((size_t)E * 4);
    float*  CW    = (float*)alloc((size_t)E * 4);
    float*  RED   = (float*)alloc((size_t)NRED * RSTRIDE * 4);

    hipMemsetAsync(CNT, 0, (size_t)N * 4, stream);
    hipMemsetAsync(CUR, 0, (size_t)N * 4, stream);
    hipMemsetAsync(DEG, 0, (size_t)N * 4, stream);
    hipMemsetAsync(RED, 0, (size_t)NRED * RSTRIDE * 4, stream);

    int eb = (E + 255) / 256;
    castw_kernel<<<dim3(16, 16), dim3(16, 16), 0, stream>>>(W1, WT);
    hist_kernel<<<eb, 256, 0, stream>>>(esrc, edst, CNT, DEG, E);
    scan_kernel<<<1, 1024, 0, stream>>>(CNT, ROFF, N);
    scatter_kernel<<<eb, 256, 0, stream>>>(esrc, edst, ew, ROFF, CUR, CDST, CW, E);

    dim3 gg(2, (N + 127) / 128);
    gemm_xw_kernel<<<gg, 256, 0, stream>>>(feat, WT, XWs, N);
    gemm_xw_kernel<<<gg, 256, 0, stream>>>(faug, WT, XWt, N);

    int sb = 8 * ((N + 3) / 4);
    spmm_h_chunk_kernel<<<sb, 256, 0, stream>>>(XWs, ROFF, CDST, CW, b1, Gs, N);
    spmm_h_chunk_kernel<<<sb, 256, 0, stream>>>(XWt, ROFF, CDST, CW, b1, Gt, N);

    gemm_k_kernel<<<(N + 3) / 4, 256, 0, stream>>>(Gs, Wsm, GS_s, N);
    spmm_k_softmax<<<(N + 15) / 16, 256, 0, stream>>>(GS_s, ROFF, CDST, CW, bsv, ASG_S, N);
    gemm_k_kernel<<<(N + 3) / 4, 256, 0, stream>>>(Gt, Wtm, GS_t, N);
    spmm_k_softmax<<<(N + 15) / 16, 256, 0, stream>>>(GS_t, ROFF, CDST, CW, btv, ASG_T, N);

    node_stats_kernel<<<128, 256, 0, stream>>>(ASG_S, ASG_T, DEG, RED, N);
    edge_trace_kernel<<<256, 256, 0, stream>>>(esrc, edst, ASG_S, RED, E);
    finalize_kernel<<<1, 1, 0, stream>>>(RED, (float*)d_out, N, E);
}

// Round 5
// 475.508 us; speedup vs baseline: 1.9112x; 1.9112x over previous
//
#include <hip/hip_runtime.h>
#include <math.h>

constexpr int Fdim = 256;
constexpr int Hdim = 256;
constexpr int Kc   = 16;

constexpr int RSTRIDE = 32;
constexpr int NRED    = 34;   // 0..15 nl, 16..31 cluster_sizes, 32 con, 33 trace

typedef __attribute__((ext_vector_type(8))) short s8v;   // 8 bf16 (4 VGPRs)
typedef __attribute__((ext_vector_type(4))) float f4v;   // 4 fp32 acc

__device__ __forceinline__ float selu1(float x){
    const float scale = 1.0507009873554805f;
    const float alpha = 1.6732632423543772f;
    return scale * (x > 0.f ? x : alpha * expm1f(x));
}

__device__ __forceinline__ ushort f2bf(float x){
    union { float f; unsigned u; } c; c.f = x;
    unsigned r = c.u + 0x7fffu + ((c.u >> 16) & 1u);   // RNE
    return (ushort)(r >> 16);
}

__device__ __forceinline__ float bf2f(ushort b){
    union { unsigned u; float f; } c; c.u = ((unsigned)b) << 16;
    return c.f;
}

// ---------------- CSR build ----------------
__global__ void hist_kernel(const int* __restrict__ src, const int* __restrict__ dst,
                            int* __restrict__ scnt, int* __restrict__ dcnt, int E){
    int i = blockIdx.x * blockDim.x + threadIdx.x;
    if (i < E){
        atomicAdd(&scnt[src[i]], 1);
        atomicAdd(&dcnt[dst[i]], 1);
    }
}

__global__ void scan_kernel(const int* __restrict__ cnt, int* __restrict__ roff, int n){
    __shared__ int sums[1024];
    int t = threadIdx.x;
    int chunk = (n + 1023) / 1024;
    int lo = t * chunk;
    int hi = min(lo + chunk, n);
    int s = 0;
    for (int i = lo; i < hi; ++i) s += cnt[i];
    sums[t] = s;
    __syncthreads();
    for (int off = 1; off < 1024; off <<= 1){
        int v = (t >= off) ? sums[t - off] : 0;
        __syncthreads();
        sums[t] += v;
        __syncthreads();
    }
    int run = sums[t] - s;  // exclusive prefix
    for (int i = lo; i < hi; ++i){ roff[i] = run; run += cnt[i]; }
    if (t == 1023) roff[n] = sums[1023];
}

__global__ void scatter_kernel(const int* __restrict__ src, const int* __restrict__ dst,
                               const float* __restrict__ w, const int* __restrict__ roff,
                               int* __restrict__ cur, int* __restrict__ cdst,
                               float* __restrict__ cw, int E){
    int i = blockIdx.x * blockDim.x + threadIdx.x;
    if (i < E){
        int s = src[i];
        int p = roff[s] + atomicAdd(&cur[s], 1);
        cdst[p] = dst[i];
        cw[p]   = w[i];
    }
}

// ---------------- W1 transpose-cast: Wt[n][k] = bf16(W1[k][n]) ----------------
__global__ void castw_kernel(const float* __restrict__ W, ushort* __restrict__ Wt){
    __shared__ float t[16][17];
    int tx = threadIdx.x, ty = threadIdx.y;
    int k  = blockIdx.y * 16 + ty;
    int nn = blockIdx.x * 16 + tx;
    t[ty][tx] = W[k * 256 + nn];
    __syncthreads();
    int n2 = blockIdx.x * 16 + ty;
    int k2 = blockIdx.y * 16 + tx;
    Wt[n2 * 256 + k2] = f2bf(t[tx][ty]);
}

// ---------------- Ws/Wt transpose-cast: WT[c][h] = bf16(W[h][c]), [256,16]->[16][256] ----
__global__ void castwk_kernel(const float* __restrict__ Ws, const float* __restrict__ Wt,
                              ushort* __restrict__ WsT, ushort* __restrict__ WtT){
    int h = threadIdx.x;   // 0..255
    #pragma unroll
    for (int c = 0; c < 16; ++c){
        WsT[c * 256 + h] = f2bf(Ws[h * 16 + c]);
        WtT[c * 256 + h] = f2bf(Wt[h * 16 + c]);
    }
}

// ---------------- MFMA bf16 GEMM: C_bf16[M][256] = A_f32[M][256] @ W (Bt[n][k] bf16) ----
__global__ __launch_bounds__(256, 2) void gemm_xw_kernel(
        const float* __restrict__ A, const ushort* __restrict__ Bt,
        ushort* __restrict__ C, int M){
    __shared__ ushort blds[32768];
    int tid = threadIdx.x;
    int n0  = blockIdx.x * 128;
    int bm  = blockIdx.y * 128;

    #pragma unroll
    for (int j = 0; j < 16; ++j){
        int c  = j * 256 + tid;
        int nl = c >> 5, kc = c & 31;
        uint4 v = *reinterpret_cast<const uint4*>(Bt + (((size_t)(n0 + nl)) << 8) + (kc << 3));
        unsigned boff = (unsigned)(((nl << 9) + (kc << 4)) ^ ((nl & 7) << 4));
        *reinterpret_cast<uint4*>(reinterpret_cast<char*>(blds) + boff) = v;
    }
    __syncthreads();

    int w = tid >> 6, l = tid & 63;
    int lr = l & 15, lk = l >> 4;

    f4v acc[2][8];
    #pragma unroll
    for (int m = 0; m < 2; ++m)
        #pragma unroll
        for (int t = 0; t < 8; ++t)
            acc[m][t] = (f4v){0.f, 0.f, 0.f, 0.f};

    int r0 = bm + w * 32 + lr;
    int r1 = r0 + 16;
    int rc0 = min(r0, M - 1), rc1 = min(r1, M - 1);
    const float* a0 = A + (size_t)rc0 * 256 + lk * 8;
    const float* a1 = A + (size_t)rc1 * 256 + lk * 8;

    for (int ks = 0; ks < 8; ++ks){
        s8v af0, af1;
        {
            float4 f0 = *reinterpret_cast<const float4*>(a0 + ks * 32);
            float4 f1 = *reinterpret_cast<const float4*>(a0 + ks * 32 + 4);
            af0[0] = (short)f2bf(f0.x); af0[1] = (short)f2bf(f0.y);
            af0[2] = (short)f2bf(f0.z); af0[3] = (short)f2bf(f0.w);
            af0[4] = (short)f2bf(f1.x); af0[5] = (short)f2bf(f1.y);
            af0[6] = (short)f2bf(f1.z); af0[7] = (short)f2bf(f1.w);
        }
        {
            float4 f0 = *reinterpret_cast<const float4*>(a1 + ks * 32);
            float4 f1 = *reinterpret_cast<const float4*>(a1 + ks * 32 + 4);
            af1[0] = (short)f2bf(f0.x); af1[1] = (short)f2bf(f0.y);
            af1[2] = (short)f2bf(f0.z); af1[3] = (short)f2bf(f0.w);
            af1[4] = (short)f2bf(f1.x); af1[5] = (short)f2bf(f1.y);
            af1[6] = (short)f2bf(f1.z); af1[7] = (short)f2bf(f1.w);
        }
        #pragma unroll
        for (int t = 0; t < 8; ++t){
            int nl = t * 16 + lr;
            unsigned boff = (unsigned)(((nl << 9) + ((ks * 4 + lk) << 4)) ^ ((nl & 7) << 4));
            s8v bf = *reinterpret_cast<const s8v*>(reinterpret_cast<const char*>(blds) + boff);
            acc[0][t] = __builtin_amdgcn_mfma_f32_16x16x32_bf16(af0, bf, acc[0][t], 0, 0, 0);
            acc[1][t] = __builtin_amdgcn_mfma_f32_16x16x32_bf16(af1, bf, acc[1][t], 0, 0, 0);
        }
    }

    #pragma unroll
    for (int m = 0; m < 2; ++m){
        #pragma unroll
        for (int t = 0; t < 8; ++t){
            int col = n0 + t * 16 + lr;
            #pragma unroll
            for (int j = 0; j < 4; ++j){
                int row = bm + w * 32 + m * 16 + lk * 4 + j;
                if (row < M) C[(size_t)row * 256 + col] = f2bf(acc[m][t][j]);
            }
        }
    }
}

// ---------------- fused SPMM over H=256 for student+teacher, + bias + selu ----------------
__global__ __launch_bounds__(256) void spmm_h2_kernel(
        const ushort* __restrict__ XWs, const ushort* __restrict__ XWt,
        const int* __restrict__ roff, const int* __restrict__ cdst,
        const float* __restrict__ cw, const float* __restrict__ b1,
        ushort* __restrict__ Gs, ushort* __restrict__ Gt, int n){
    int wid = threadIdx.x >> 6, lane = threadIdx.x & 63;
    int r = blockIdx.x * 4 + wid;
    if (r >= n) return;
    int e0 = roff[r], e1 = roff[r + 1];
    float s0 = 0.f, s1 = 0.f, s2 = 0.f, s3 = 0.f;
    float t0 = 0.f, t1 = 0.f, t2 = 0.f, t3 = 0.f;
    for (int e = e0; e < e1; ++e){
        int d   = cdst[e];
        float w = cw[e];
        ushort4 xs = *reinterpret_cast<const ushort4*>(XWs + (((size_t)d) << 8) + lane * 4);
        ushort4 xt = *reinterpret_cast<const ushort4*>(XWt + (((size_t)d) << 8) + lane * 4);
        s0 = fmaf(w, bf2f(xs.x), s0); s1 = fmaf(w, bf2f(xs.y), s1);
        s2 = fmaf(w, bf2f(xs.z), s2); s3 = fmaf(w, bf2f(xs.w), s3);
        t0 = fmaf(w, bf2f(xt.x), t0); t1 = fmaf(w, bf2f(xt.y), t1);
        t2 = fmaf(w, bf2f(xt.z), t2); t3 = fmaf(w, bf2f(xt.w), t3);
    }
    float4 bb = *reinterpret_cast<const float4*>(b1 + lane * 4);
    ushort4 os = make_ushort4(f2bf(selu1(s0 + bb.x)), f2bf(selu1(s1 + bb.y)),
                              f2bf(selu1(s2 + bb.z)), f2bf(selu1(s3 + bb.w)));
    ushort4 ot = make_ushort4(f2bf(selu1(t0 + bb.x)), f2bf(selu1(t1 + bb.y)),
                              f2bf(selu1(t2 + bb.z)), f2bf(selu1(t3 + bb.w)));
    *reinterpret_cast<ushort4*>(Gs + (((size_t)r) << 8) + lane * 4) = os;
    *reinterpret_cast<ushort4*>(Gt + (((size_t)r) << 8) + lane * 4) = ot;
}

// ---------------- fused MFMA: GS_s = Gs@Ws, GS_t = Gt@Wt   [N,256]x[256,16] ----------
// one wave per 16 rows; B = WT[col][k] bf16 (16x256)
__global__ __launch_bounds__(256) void gemm_k2_kernel(
        const ushort* __restrict__ Gs, const ushort* __restrict__ Gt,
        const ushort* __restrict__ WsT, const ushort* __restrict__ WtT,
        float* __restrict__ GS_s, float* __restrict__ GS_t, int n){
    int wv = blockIdx.x * 4 + (threadIdx.x >> 6);
    int l  = threadIdx.x & 63;
    int lr = l & 15, lk = l >> 4;
    int nw = (n + 15) >> 4;
    if (wv >= nw) return;
    int r0 = wv * 16;

    s8v bs_[8], bt_[8];
    #pragma unroll
    for (int ks = 0; ks < 8; ++ks){
        bs_[ks] = *reinterpret_cast<const s8v*>(WsT + lr * 256 + ks * 32 + lk * 8);
        bt_[ks] = *reinterpret_cast<const s8v*>(WtT + lr * 256 + ks * 32 + lk * 8);
    }

    f4v accs = (f4v){0.f,0.f,0.f,0.f}, acct = (f4v){0.f,0.f,0.f,0.f};
    int row = min(r0 + lr, n - 1);
    const ushort* gsrow = Gs + (size_t)row * 256 + lk * 8;
    const ushort* gtrow = Gt + (size_t)row * 256 + lk * 8;
    #pragma unroll
    for (int ks = 0; ks < 8; ++ks){
        s8v a_s = *reinterpret_cast<const s8v*>(gsrow + ks * 32);
        s8v a_t = *reinterpret_cast<const s8v*>(gtrow + ks * 32);
        accs = __builtin_amdgcn_mfma_f32_16x16x32_bf16(a_s, bs_[ks], accs, 0, 0, 0);
        acct = __builtin_amdgcn_mfma_f32_16x16x32_bf16(a_t, bt_[ks], acct, 0, 0, 0);
    }
    #pragma unroll
    for (int j = 0; j < 4; ++j){
        int rr = r0 + lk * 4 + j;
        if (rr < n){
            GS_s[(size_t)rr * 16 + lr] = accs[j];
            GS_t[(size_t)rr * 16 + lr] = acct[j];
        }
    }
}

// ---------------- fused: SPMM-K + softmax (both branches) + node stats ----------------
// 16-lane groups; grid-stride over rows. Writes ASG_S; accumulates nl/cs/con into red.
__global__ __launch_bounds__(256) void spmm_k2_kernel(
        const float* __restrict__ GS_s, const float* __restrict__ GS_t,
        const int* __restrict__ roff, const int* __restrict__ cdst,
        const float* __restrict__ cw, const float* __restrict__ bsv,
        const float* __restrict__ btv, const int* __restrict__ deg,
        float* __restrict__ asg, float* __restrict__ red, int n){
    int tid  = threadIdx.x;
    int lane = tid & 63;
    int j    = lane & 15;
    int gidx    = blockIdx.x * 16 + (tid >> 4);
    int gstride = gridDim.x * 16;
    float bs_ = bsv[j], bt_ = btv[j];
    float nl_l = 0.f, cs_l = 0.f, con_l = 0.f;

    for (int r = gidx; r < n; r += gstride){
        int e0 = roff[r], e1 = roff[r + 1];
        float as_ = 0.f, at_ = 0.f;
        for (int e = e0; e < e1; ++e){
            int d   = cdst[e];
            float w = cw[e];
            as_ = fmaf(w, GS_s[(size_t)d * 16 + j], as_);
            at_ = fmaf(w, GS_t[(size_t)d * 16 + j], at_);
        }
        float xs = selu1(as_ + bs_);
        float xt = selu1(at_ + bt_);
        float ms = xs, mt = xt;
        #pragma unroll
        for (int off = 8; off >= 1; off >>= 1){
            ms = fmaxf(ms, __shfl_xor(ms, off));
            mt = fmaxf(mt, __shfl_xor(mt, off));
        }
        float es = expf(xs - ms), et = expf(xt - mt);
        float ss = es, st = et;
        #pragma unroll
        for (int off = 8; off >= 1; off >>= 1){
            ss += __shfl_xor(ss, off);
            st += __shfl_xor(st, off);
        }
        float a = es / ss, b = et / st;
        asg[(size_t)r * 16 + j] = a;
        float dgr = (float)deg[r];
        nl_l += a * dgr;
        cs_l += a;
        float dot = a * b, na = a * a, nb = b * b;
        #pragma unroll
        for (int off = 8; off >= 1; off >>= 1){
            dot += __shfl_xor(dot, off);
            na  += __shfl_xor(na, off);
            nb  += __shfl_xor(nb, off);
        }
        if (j == 0){
            na = fmaxf(sqrtf(na), 1e-12f);
            nb = fmaxf(sqrtf(nb), 1e-12f);
            con_l += 2.f - 2.f * dot / (na * nb);
        }
    }

    // combine the 4 groups within each wave: lanes {l, l^16, l^32, l^48}
    nl_l  += __shfl_xor(nl_l, 16);  nl_l  += __shfl_xor(nl_l, 32);
    cs_l  += __shfl_xor(cs_l, 16);  cs_l  += __shfl_xor(cs_l, 32);
    con_l += __shfl_xor(con_l, 16); con_l += __shfl_xor(con_l, 32);

    __shared__ float part[4][33];
    int wid = tid >> 6;
    if (lane < 16){
        part[wid][lane]      = nl_l;
        part[wid][16 + lane] = cs_l;
    }
    if (lane == 0) part[wid][32] = con_l;
    __syncthreads();
    if (tid < 33){
        float s = part[0][tid] + part[1][tid] + part[2][tid] + part[3][tid];
        atomicAdd(&red[tid * RSTRIDE], s);
    }
}

// ---------------- per-edge trace: sum_e dot(S[src], S[dst]) ----------------
__global__ __launch_bounds__(256) void edge_trace_kernel(const int* __restrict__ src,
        const int* __restrict__ dst, const float* __restrict__ as_,
        float* __restrict__ red, int E){
    int tid    = blockIdx.x * blockDim.x + threadIdx.x;
    int stride = gridDim.x * blockDim.x;
    float dot = 0.f;
    for (int i = tid; i < E; i += stride){
        const float4* pa = reinterpret_cast<const float4*>(as_ + (size_t)src[i] * 16);
        const float4* pb = reinterpret_cast<const float4*>(as_ + (size_t)dst[i] * 16);
        #pragma unroll
        for (int q = 0; q < 4; ++q){
            float4 va = pa[q]; float4 vb = pb[q];
            dot = fmaf(va.x, vb.x, dot); dot = fmaf(va.y, vb.y, dot);
            dot = fmaf(va.z, vb.z, dot); dot = fmaf(va.w, vb.w, dot);
        }
    }
    #pragma unroll
    for (int off = 1; off < 64; off <<= 1) dot += __shfl_xor(dot, off);
    __shared__ float part[4];
    int wid = threadIdx.x >> 6, lane = threadIdx.x & 63;
    if (lane == 0) part[wid] = dot;
    __syncthreads();
    if (threadIdx.x == 0)
        atomicAdd(&red[33 * RSTRIDE], part[0] + part[1] + part[2] + part[3]);
}

// ---------------- finalize ----------------
__global__ void finalize_kernel(const float* __restrict__ red, float* __restrict__ out,
                                int n, int E){
    float trace = red[33 * RSTRIDE];
    float nl2 = 0.f, cs2 = 0.f;
    #pragma unroll
    for (int k = 0; k < 16; ++k){
        nl2 = fmaf(red[k * RSTRIDE],        red[k * RSTRIDE],        nl2);
        cs2 = fmaf(red[(16 + k) * RSTRIDE], red[(16 + k) * RSTRIDE], cs2);
    }
    float twoE = 2.f * (float)E;
    float spectral = -(trace - nl2 / twoE) / twoE;
    float cluster  = sqrtf(cs2) / (float)n * 4.f - 1.f;
    float con      = red[32 * RSTRIDE] / (float)n;
    out[0] = spectral + cluster + con;
}

extern "C" void kernel_launch(void* const* d_in, const int* in_sizes, int n_in,
                              void* d_out, int out_size, void* d_ws, size_t ws_size,
                              hipStream_t stream){
    const int*   esrc = (const int*)d_in[0];
    const int*   edst = (const int*)d_in[1];
    const float* ew   = (const float*)d_in[2];
    const float* feat = (const float*)d_in[3];
    const float* faug = (const float*)d_in[4];
    const float* W1   = (const float*)d_in[5];
    const float* b1   = (const float*)d_in[6];
    const float* Wsm  = (const float*)d_in[7];
    const float* bsv  = (const float*)d_in[8];
    const float* Wtm  = (const float*)d_in[9];
    const float* btv  = (const float*)d_in[10];
    int E = in_sizes[0];
    int N = in_sizes[3] / Fdim;

    char* ws = (char*)d_ws;
    size_t off = 0;
    auto alloc = [&](size_t bytes) -> char* {
        char* p = ws + off;
        off = (off + bytes + 255) & ~(size_t)255;
        return p;
    };
    ushort* XWs   = (ushort*)alloc((size_t)N * Hdim * 2);
    ushort* XWt   = (ushort*)alloc((size_t)N * Hdim * 2);
    ushort* Gs    = (ushort*)alloc((size_t)N * Hdim * 2);
    ushort* Gt    = (ushort*)alloc((size_t)N * Hdim * 2);
    float*  GS_s  = (float*)alloc((size_t)N * Kc * 4);
    float*  GS_t  = (float*)alloc((size_t)N * Kc * 4);
    float*  ASG_S = (float*)alloc((size_t)N * Kc * 4);
    ushort* WT    = (ushort*)alloc((size_t)256 * 256 * 2);
    ushort* WsT   = (ushort*)alloc((size_t)16 * 256 * 2);
    ushort* WtT   = (ushort*)alloc((size_t)16 * 256 * 2);
    int*    ROFF  = (int*)alloc((size_t)(N + 1) * 4);
    int*    CNT   = (int*)alloc((size_t)N * 4);
    int*    CUR   = (int*)alloc((size_t)N * 4);
    int*    DEG   = (int*)alloc((size_t)N * 4);
    int*    CDST  = (int*)alloc((size_t)E * 4);
    float*  CW    = (float*)alloc((size_t)E * 4);
    float*  RED   = (float*)alloc((size_t)NRED * RSTRIDE * 4);

    hipMemsetAsync(CNT, 0, (size_t)N * 4, stream);
    hipMemsetAsync(CUR, 0, (size_t)N * 4, stream);
    hipMemsetAsync(DEG, 0, (size_t)N * 4, stream);
    hipMemsetAsync(RED, 0, (size_t)NRED * RSTRIDE * 4, stream);

    int eb = (E + 255) / 256;
    castw_kernel<<<dim3(16, 16), dim3(16, 16), 0, stream>>>(W1, WT);
    castwk_kernel<<<1, 256, 0, stream>>>(Wsm, Wtm, WsT, WtT);
    hist_kernel<<<eb, 256, 0, stream>>>(esrc, edst, CNT, DEG, E);
    scan_kernel<<<1, 1024, 0, stream>>>(CNT, ROFF, N);
    scatter_kernel<<<eb, 256, 0, stream>>>(esrc, edst, ew, ROFF, CUR, CDST, CW, E);

    dim3 gg(2, (N + 127) / 128);
    gemm_xw_kernel<<<gg, 256, 0, stream>>>(feat, WT, XWs, N);
    gemm_xw_kernel<<<gg, 256, 0, stream>>>(faug, WT, XWt, N);

    spmm_h2_kernel<<<(N + 3) / 4, 256, 0, stream>>>(XWs, XWt, ROFF, CDST, CW, b1, Gs, Gt, N);

    int nw = (N + 15) / 16;
    gemm_k2_kernel<<<(nw + 3) / 4, 256, 0, stream>>>(Gs, Gt, WsT, WtT, GS_s, GS_t, N);

    spmm_k2_kernel<<<1024, 256, 0, stream>>>(GS_s, GS_t, ROFF, CDST, CW, bsv, btv,
                                             DEG, ASG_S, RED, N);

    edge_trace_kernel<<<256, 256, 0, stream>>>(esrc, edst, ASG_S, RED, E);
    finalize_kernel<<<1, 1, 0, stream>>>(RED, (float*)d_out, N, E);
}

// Round 6
// 405.203 us; speedup vs baseline: 2.2428x; 1.1735x over previous
//
#include <hip/hip_runtime.h>
#include <math.h>

constexpr int Fdim = 256;
constexpr int Hdim = 256;
constexpr int Kc   = 16;

constexpr int RSTRIDE = 32;
constexpr int NRED    = 34;   // 0..15 nl, 16..31 cluster_sizes, 32 con, 33 trace

typedef __attribute__((ext_vector_type(8))) short s8v;   // 8 bf16 (4 VGPRs)
typedef __attribute__((ext_vector_type(4))) float f4v;   // 4 fp32 acc

__device__ __forceinline__ float selu1(float x){
    const float scale = 1.0507009873554805f;
    const float alpha = 1.6732632423543772f;
    return scale * (x > 0.f ? x : alpha * expm1f(x));
}

__device__ __forceinline__ ushort f2bf(float x){
    union { float f; unsigned u; } c; c.f = x;
    unsigned r = c.u + 0x7fffu + ((c.u >> 16) & 1u);   // RNE
    return (ushort)(r >> 16);
}

__device__ __forceinline__ float bf2f(ushort b){
    union { unsigned u; float f; } c; c.u = ((unsigned)b) << 16;
    return c.f;
}

__device__ __forceinline__ float bflo(unsigned v){
    union { unsigned u; float f; } c; c.u = v << 16; return c.f;
}
__device__ __forceinline__ float bfhi(unsigned v){
    union { unsigned u; float f; } c; c.u = v & 0xffff0000u; return c.f;
}

// ---------------- CSR build ----------------
__global__ void hist_kernel(const int* __restrict__ src, const int* __restrict__ dst,
                            int* __restrict__ scnt, int* __restrict__ dcnt, int E){
    int i = blockIdx.x * blockDim.x + threadIdx.x;
    if (i < E){
        atomicAdd(&scnt[src[i]], 1);
        atomicAdd(&dcnt[dst[i]], 1);
    }
}

// hierarchical scan: (1) block sums, (2) scan of block sums, (3) local scan + offset
__global__ __launch_bounds__(256) void scan1_kernel(const int* __restrict__ cnt,
                                                    int* __restrict__ bsum, int n){
    int i = blockIdx.x * 256 + threadIdx.x;
    int v = (i < n) ? cnt[i] : 0;
    #pragma unroll
    for (int off = 1; off < 64; off <<= 1) v += __shfl_xor(v, off);
    __shared__ int sdata[4];
    int wid = threadIdx.x >> 6, lane = threadIdx.x & 63;
    if (lane == 0) sdata[wid] = v;
    __syncthreads();
    if (threadIdx.x == 0) bsum[blockIdx.x] = sdata[0] + sdata[1] + sdata[2] + sdata[3];
}

__global__ __launch_bounds__(256) void scan2_kernel(int* __restrict__ bsum, int nb){
    __shared__ int s[256];
    int t = threadIdx.x;
    int v = (t < nb) ? bsum[t] : 0;
    s[t] = v;
    __syncthreads();
    for (int off = 1; off < 256; off <<= 1){
        int x = (t >= off) ? s[t - off] : 0;
        __syncthreads();
        s[t] += x;
        __syncthreads();
    }
    if (t < nb) bsum[t] = s[t] - v;   // exclusive
}

__global__ __launch_bounds__(256) void scan3_kernel(const int* __restrict__ cnt,
        const int* __restrict__ bsum, int* __restrict__ roff, int n){
    __shared__ int ls[256];
    int t = threadIdx.x;
    int i = blockIdx.x * 256 + t;
    int v = (i < n) ? cnt[i] : 0;
    ls[t] = v;
    __syncthreads();
    for (int off = 1; off < 256; off <<= 1){
        int x = (t >= off) ? ls[t - off] : 0;
        __syncthreads();
        ls[t] += x;
        __syncthreads();
    }
    int base = bsum[blockIdx.x];
    if (i < n)  roff[i] = base + ls[t] - v;
    if (i == n - 1) roff[n] = base + ls[t];
}

__global__ void scatter_kernel(const int* __restrict__ src, const int* __restrict__ dst,
                               const float* __restrict__ w, const int* __restrict__ roff,
                               int* __restrict__ cur, int* __restrict__ cdst,
                               float* __restrict__ cw, int E){
    int i = blockIdx.x * blockDim.x + threadIdx.x;
    if (i < E){
        int s = src[i];
        int p = roff[s] + atomicAdd(&cur[s], 1);
        cdst[p] = dst[i];
        cw[p]   = w[i];
    }
}

// ---------------- W1 transpose-cast: Wt[n][k] = bf16(W1[k][n]) ----------------
__global__ void castw_kernel(const float* __restrict__ W, ushort* __restrict__ Wt){
    __shared__ float t[16][17];
    int tx = threadIdx.x, ty = threadIdx.y;
    int k  = blockIdx.y * 16 + ty;
    int nn = blockIdx.x * 16 + tx;
    t[ty][tx] = W[k * 256 + nn];
    __syncthreads();
    int n2 = blockIdx.x * 16 + ty;
    int k2 = blockIdx.y * 16 + tx;
    Wt[n2 * 256 + k2] = f2bf(t[tx][ty]);
}

// ---------------- Ws/Wt transpose-cast: WT[c][h] = bf16(W[h][c]), [256,16]->[16][256] ----
__global__ void castwk_kernel(const float* __restrict__ Ws, const float* __restrict__ Wt,
                              ushort* __restrict__ WsT, ushort* __restrict__ WtT){
    int h = threadIdx.x;   // 0..255
    #pragma unroll
    for (int c = 0; c < 16; ++c){
        WsT[c * 256 + h] = f2bf(Ws[h * 16 + c]);
        WtT[c * 256 + h] = f2bf(Wt[h * 16 + c]);
    }
}

// ---------------- MFMA bf16 GEMM: C_bf16[M][256] = A_f32[M][256] @ W (Bt[n][k] bf16) ----
__global__ __launch_bounds__(256, 2) void gemm_xw_kernel(
        const float* __restrict__ A, const ushort* __restrict__ Bt,
        ushort* __restrict__ C, int M){
    __shared__ ushort blds[32768];
    int tid = threadIdx.x;
    int n0  = blockIdx.x * 128;
    int bm  = blockIdx.y * 128;

    #pragma unroll
    for (int j = 0; j < 16; ++j){
        int c  = j * 256 + tid;
        int nl = c >> 5, kc = c & 31;
        uint4 v = *reinterpret_cast<const uint4*>(Bt + (((size_t)(n0 + nl)) << 8) + (kc << 3));
        unsigned boff = (unsigned)(((nl << 9) + (kc << 4)) ^ ((nl & 7) << 4));
        *reinterpret_cast<uint4*>(reinterpret_cast<char*>(blds) + boff) = v;
    }
    __syncthreads();

    int w = tid >> 6, l = tid & 63;
    int lr = l & 15, lk = l >> 4;

    f4v acc[2][8];
    #pragma unroll
    for (int m = 0; m < 2; ++m)
        #pragma unroll
        for (int t = 0; t < 8; ++t)
            acc[m][t] = (f4v){0.f, 0.f, 0.f, 0.f};

    int r0 = bm + w * 32 + lr;
    int r1 = r0 + 16;
    int rc0 = min(r0, M - 1), rc1 = min(r1, M - 1);
    const float* a0 = A + (size_t)rc0 * 256 + lk * 8;
    const float* a1 = A + (size_t)rc1 * 256 + lk * 8;

    for (int ks = 0; ks < 8; ++ks){
        s8v af0, af1;
        {
            float4 f0 = *reinterpret_cast<const float4*>(a0 + ks * 32);
            float4 f1 = *reinterpret_cast<const float4*>(a0 + ks * 32 + 4);
            af0[0] = (short)f2bf(f0.x); af0[1] = (short)f2bf(f0.y);
            af0[2] = (short)f2bf(f0.z); af0[3] = (short)f2bf(f0.w);
            af0[4] = (short)f2bf(f1.x); af0[5] = (short)f2bf(f1.y);
            af0[6] = (short)f2bf(f1.z); af0[7] = (short)f2bf(f1.w);
        }
        {
            float4 f0 = *reinterpret_cast<const float4*>(a1 + ks * 32);
            float4 f1 = *reinterpret_cast<const float4*>(a1 + ks * 32 + 4);
            af1[0] = (short)f2bf(f0.x); af1[1] = (short)f2bf(f0.y);
            af1[2] = (short)f2bf(f0.z); af1[3] = (short)f2bf(f0.w);
            af1[4] = (short)f2bf(f1.x); af1[5] = (short)f2bf(f1.y);
            af1[6] = (short)f2bf(f1.z); af1[7] = (short)f2bf(f1.w);
        }
        #pragma unroll
        for (int t = 0; t < 8; ++t){
            int nl = t * 16 + lr;
            unsigned boff = (unsigned)(((nl << 9) + ((ks * 4 + lk) << 4)) ^ ((nl & 7) << 4));
            s8v bf = *reinterpret_cast<const s8v*>(reinterpret_cast<const char*>(blds) + boff);
            acc[0][t] = __builtin_amdgcn_mfma_f32_16x16x32_bf16(af0, bf, acc[0][t], 0, 0, 0);
            acc[1][t] = __builtin_amdgcn_mfma_f32_16x16x32_bf16(af1, bf, acc[1][t], 0, 0, 0);
        }
    }

    #pragma unroll
    for (int m = 0; m < 2; ++m){
        #pragma unroll
        for (int t = 0; t < 8; ++t){
            int col = n0 + t * 16 + lr;
            #pragma unroll
            for (int j = 0; j < 4; ++j){
                int row = bm + w * 32 + m * 16 + lk * 4 + j;
                if (row < M) C[(size_t)row * 256 + col] = f2bf(acc[m][t][j]);
            }
        }
    }
}

// ---------------- fused SPMM over H=256 (student+teacher), + bias + selu ----------------
// one wave per row; lanes 0-31 student, 32-63 teacher; each lane: 8 cols, 16B gathers.
// 4-edge manual unroll for MLP.
__global__ __launch_bounds__(256) void spmm_h2_kernel(
        const ushort* __restrict__ XWs, const ushort* __restrict__ XWt,
        const int* __restrict__ roff, const int* __restrict__ cdst,
        const float* __restrict__ cw, const float* __restrict__ b1,
        ushort* __restrict__ Gs, ushort* __restrict__ Gt, int n){
    int wid = threadIdx.x >> 6, lane = threadIdx.x & 63;
    int r = blockIdx.x * 4 + wid;
    if (r >= n) return;
    int half = lane >> 5;          // 0 = student, 1 = teacher
    int hl   = lane & 31;          // col group: cols hl*8 .. hl*8+7
    const ushort* rowbase = (half ? XWt : XWs) + hl * 8;
    int e0 = roff[r], e1 = roff[r + 1];
    float acc[8] = {};

    #define ACCUM8(V, W) do{                                         \
        unsigned dw_[4] = {(V).x, (V).y, (V).z, (V).w};              \
        _Pragma("unroll")                                            \
        for (int q_ = 0; q_ < 4; ++q_){                              \
            acc[2*q_]   = fmaf((W), bflo(dw_[q_]), acc[2*q_]);       \
            acc[2*q_+1] = fmaf((W), bfhi(dw_[q_]), acc[2*q_+1]);     \
        } }while(0)

    int e = e0;
    for (; e + 3 < e1; e += 4){
        int d0 = cdst[e],     d1 = cdst[e + 1];
        int d2 = cdst[e + 2], d3 = cdst[e + 3];
        float w0 = cw[e],     w1 = cw[e + 1];
        float w2 = cw[e + 2], w3 = cw[e + 3];
        uint4 v0 = *reinterpret_cast<const uint4*>(rowbase + ((size_t)d0 << 8));
        uint4 v1 = *reinterpret_cast<const uint4*>(rowbase + ((size_t)d1 << 8));
        uint4 v2 = *reinterpret_cast<const uint4*>(rowbase + ((size_t)d2 << 8));
        uint4 v3 = *reinterpret_cast<const uint4*>(rowbase + ((size_t)d3 << 8));
        ACCUM8(v0, w0); ACCUM8(v1, w1); ACCUM8(v2, w2); ACCUM8(v3, w3);
    }
    for (; e < e1; ++e){
        int d   = cdst[e];
        float w = cw[e];
        uint4 v = *reinterpret_cast<const uint4*>(rowbase + ((size_t)d << 8));
        ACCUM8(v, w);
    }
    #undef ACCUM8

    const float* bp = b1 + hl * 8;
    float4 bb0 = *reinterpret_cast<const float4*>(bp);
    float4 bb1 = *reinterpret_cast<const float4*>(bp + 4);
    float bv[8] = {bb0.x, bb0.y, bb0.z, bb0.w, bb1.x, bb1.y, bb1.z, bb1.w};
    ushort o[8];
    #pragma unroll
    for (int q = 0; q < 8; ++q) o[q] = f2bf(selu1(acc[q] + bv[q]));
    uint4 ov = *reinterpret_cast<const uint4*>(o);
    ushort* gout = (half ? Gt : Gs) + (size_t)r * Hdim + hl * 8;
    *reinterpret_cast<uint4*>(gout) = ov;
}

// ---------------- fused MFMA: GS = pack(Gs@Ws, Gt@Wt) bf16   [N,256]x[256,16] ----------
__global__ __launch_bounds__(256) void gemm_k2_kernel(
        const ushort* __restrict__ Gs, const ushort* __restrict__ Gt,
        const ushort* __restrict__ WsT, const ushort* __restrict__ WtT,
        unsigned* __restrict__ GSp, int n){
    int wv = blockIdx.x * 4 + (threadIdx.x >> 6);
    int l  = threadIdx.x & 63;
    int lr = l & 15, lk = l >> 4;
    int nw = (n + 15) >> 4;
    if (wv >= nw) return;
    int r0 = wv * 16;

    s8v bs_[8], bt_[8];
    #pragma unroll
    for (int ks = 0; ks < 8; ++ks){
        bs_[ks] = *reinterpret_cast<const s8v*>(WsT + lr * 256 + ks * 32 + lk * 8);
        bt_[ks] = *reinterpret_cast<const s8v*>(WtT + lr * 256 + ks * 32 + lk * 8);
    }

    f4v accs = (f4v){0.f,0.f,0.f,0.f}, acct = (f4v){0.f,0.f,0.f,0.f};
    int row = min(r0 + lr, n - 1);
    const ushort* gsrow = Gs + (size_t)row * 256 + lk * 8;
    const ushort* gtrow = Gt + (size_t)row * 256 + lk * 8;
    #pragma unroll
    for (int ks = 0; ks < 8; ++ks){
        s8v a_s = *reinterpret_cast<const s8v*>(gsrow + ks * 32);
        s8v a_t = *reinterpret_cast<const s8v*>(gtrow + ks * 32);
        accs = __builtin_amdgcn_mfma_f32_16x16x32_bf16(a_s, bs_[ks], accs, 0, 0, 0);
        acct = __builtin_amdgcn_mfma_f32_16x16x32_bf16(a_t, bt_[ks], acct, 0, 0, 0);
    }
    #pragma unroll
    for (int j = 0; j < 4; ++j){
        int rr = r0 + lk * 4 + j;
        if (rr < n){
            unsigned pv = (unsigned)f2bf(accs[j]) | ((unsigned)f2bf(acct[j]) << 16);
            GSp[(size_t)rr * 16 + lr] = pv;
        }
    }
}

// ---------------- fused: SPMM-K + softmax (both branches) + node stats ----------------
__global__ __launch_bounds__(256) void spmm_k2_kernel(
        const unsigned* __restrict__ GSp,
        const int* __restrict__ roff, const int* __restrict__ cdst,
        const float* __restrict__ cw, const float* __restrict__ bsv,
        const float* __restrict__ btv, const int* __restrict__ deg,
        float* __restrict__ asg, float* __restrict__ red, int n){
    int tid  = threadIdx.x;
    int lane = tid & 63;
    int j    = lane & 15;
    int gidx    = blockIdx.x * 16 + (tid >> 4);
    int gstride = gridDim.x * 16;
    float bs_ = bsv[j], bt_ = btv[j];
    float nl_l = 0.f, cs_l = 0.f, con_l = 0.f;

    for (int r = gidx; r < n; r += gstride){
        int e0 = roff[r], e1 = roff[r + 1];
        float as_ = 0.f, at_ = 0.f;
        for (int e = e0; e < e1; ++e){
            int d   = cdst[e];
            float w = cw[e];
            unsigned v = GSp[(size_t)d * 16 + j];
            as_ = fmaf(w, bflo(v), as_);
            at_ = fmaf(w, bfhi(v), at_);
        }
        float xs = selu1(as_ + bs_);
        float xt = selu1(at_ + bt_);
        float ms = xs, mt = xt;
        #pragma unroll
        for (int off = 8; off >= 1; off >>= 1){
            ms = fmaxf(ms, __shfl_xor(ms, off));
            mt = fmaxf(mt, __shfl_xor(mt, off));
        }
        float es = expf(xs - ms), et = expf(xt - mt);
        float ss = es, st = et;
        #pragma unroll
        for (int off = 8; off >= 1; off >>= 1){
            ss += __shfl_xor(ss, off);
            st += __shfl_xor(st, off);
        }
        float a = es / ss, b = et / st;
        asg[(size_t)r * 16 + j] = a;
        float dgr = (float)deg[r];
        nl_l += a * dgr;
        cs_l += a;
        float dot = a * b, na = a * a, nb = b * b;
        #pragma unroll
        for (int off = 8; off >= 1; off >>= 1){
            dot += __shfl_xor(dot, off);
            na  += __shfl_xor(na, off);
            nb  += __shfl_xor(nb, off);
        }
        if (j == 0){
            na = fmaxf(sqrtf(na), 1e-12f);
            nb = fmaxf(sqrtf(nb), 1e-12f);
            con_l += 2.f - 2.f * dot / (na * nb);
        }
    }

    nl_l  += __shfl_xor(nl_l, 16);  nl_l  += __shfl_xor(nl_l, 32);
    cs_l  += __shfl_xor(cs_l, 16);  cs_l  += __shfl_xor(cs_l, 32);
    con_l += __shfl_xor(con_l, 16); con_l += __shfl_xor(con_l, 32);

    __shared__ float part[4][33];
    int wid = tid >> 6;
    if (lane < 16){
        part[wid][lane]      = nl_l;
        part[wid][16 + lane] = cs_l;
    }
    if (lane == 0) part[wid][32] = con_l;
    __syncthreads();
    if (tid < 33){
        float s = part[0][tid] + part[1][tid] + part[2][tid] + part[3][tid];
        atomicAdd(&red[tid * RSTRIDE], s);
    }
}

// ---------------- per-edge trace: sum_e dot(S[src], S[dst]) ----------------
__global__ __launch_bounds__(256) void edge_trace_kernel(const int* __restrict__ src,
        const int* __restrict__ dst, const float* __restrict__ as_,
        float* __restrict__ red, int E){
    int tid    = blockIdx.x * blockDim.x + threadIdx.x;
    int stride = gridDim.x * blockDim.x;
    float dot = 0.f;
    for (int i = tid; i < E; i += stride){
        const float4* pa = reinterpret_cast<const float4*>(as_ + (size_t)src[i] * 16);
        const float4* pb = reinterpret_cast<const float4*>(as_ + (size_t)dst[i] * 16);
        #pragma unroll
        for (int q = 0; q < 4; ++q){
            float4 va = pa[q]; float4 vb = pb[q];
            dot = fmaf(va.x, vb.x, dot); dot = fmaf(va.y, vb.y, dot);
            dot = fmaf(va.z, vb.z, dot); dot = fmaf(va.w, vb.w, dot);
        }
    }
    #pragma unroll
    for (int off = 1; off < 64; off <<= 1) dot += __shfl_xor(dot, off);
    __shared__ float part[4];
    int wid = threadIdx.x >> 6, lane = threadIdx.x & 63;
    if (lane == 0) part[wid] = dot;
    __syncthreads();
    if (threadIdx.x == 0)
        atomicAdd(&red[33 * RSTRIDE], part[0] + part[1] + part[2] + part[3]);
}

// ---------------- finalize ----------------
__global__ void finalize_kernel(const float* __restrict__ red, float* __restrict__ out,
                                int n, int E){
    float trace = red[33 * RSTRIDE];
    float nl2 = 0.f, cs2 = 0.f;
    #pragma unroll
    for (int k = 0; k < 16; ++k){
        nl2 = fmaf(red[k * RSTRIDE],        red[k * RSTRIDE],        nl2);
        cs2 = fmaf(red[(16 + k) * RSTRIDE], red[(16 + k) * RSTRIDE], cs2);
    }
    float twoE = 2.f * (float)E;
    float spectral = -(trace - nl2 / twoE) / twoE;
    float cluster  = sqrtf(cs2) / (float)n * 4.f - 1.f;
    float con      = red[32 * RSTRIDE] / (float)n;
    out[0] = spectral + cluster + con;
}

extern "C" void kernel_launch(void* const* d_in, const int* in_sizes, int n_in,
                              void* d_out, int out_size, void* d_ws, size_t ws_size,
                              hipStream_t stream){
    const int*   esrc = (const int*)d_in[0];
    const int*   edst = (const int*)d_in[1];
    const float* ew   = (const float*)d_in[2];
    const float* feat = (const float*)d_in[3];
    const float* faug = (const float*)d_in[4];
    const float* W1   = (const float*)d_in[5];
    const float* b1   = (const float*)d_in[6];
    const float* Wsm  = (const float*)d_in[7];
    const float* bsv  = (const float*)d_in[8];
    const float* Wtm  = (const float*)d_in[9];
    const float* btv  = (const float*)d_in[10];
    int E = in_sizes[0];
    int N = in_sizes[3] / Fdim;

    char* ws = (char*)d_ws;
    size_t off = 0;
    auto alloc = [&](size_t bytes) -> char* {
        char* p = ws + off;
        off = (off + bytes + 255) & ~(size_t)255;
        return p;
    };
    ushort*   XWs   = (ushort*)alloc((size_t)N * Hdim * 2);
    ushort*   XWt   = (ushort*)alloc((size_t)N * Hdim * 2);
    ushort*   Gs    = (ushort*)alloc((size_t)N * Hdim * 2);
    ushort*   Gt    = (ushort*)alloc((size_t)N * Hdim * 2);
    unsigned* GSp   = (unsigned*)alloc((size_t)N * Kc * 4);
    float*    ASG_S = (float*)alloc((size_t)N * Kc * 4);
    ushort*   WT    = (ushort*)alloc((size_t)256 * 256 * 2);
    ushort*   WsT   = (ushort*)alloc((size_t)16 * 256 * 2);
    ushort*   WtT   = (ushort*)alloc((size_t)16 * 256 * 2);
    int*      ROFF  = (int*)alloc((size_t)(N + 1) * 4);
    int*      CNT   = (int*)alloc((size_t)N * 4);
    int*      CUR   = (int*)alloc((size_t)N * 4);
    int*      DEG   = (int*)alloc((size_t)N * 4);
    int*      BSUM  = (int*)alloc((size_t)256 * 4);
    int*      CDST  = (int*)alloc((size_t)E * 4);
    float*    CW    = (float*)alloc((size_t)E * 4);
    float*    RED   = (float*)alloc((size_t)NRED * RSTRIDE * 4);

    hipMemsetAsync(CNT, 0, (size_t)N * 4, stream);
    hipMemsetAsync(CUR, 0, (size_t)N * 4, stream);
    hipMemsetAsync(DEG, 0, (size_t)N * 4, stream);
    hipMemsetAsync(RED, 0, (size_t)NRED * RSTRIDE * 4, stream);

    int eb = (E + 255) / 256;
    int nb = (N + 255) / 256;
    castw_kernel<<<dim3(16, 16), dim3(16, 16), 0, stream>>>(W1, WT);
    castwk_kernel<<<1, 256, 0, stream>>>(Wsm, Wtm, WsT, WtT);
    hist_kernel<<<eb, 256, 0, stream>>>(esrc, edst, CNT, DEG, E);
    scan1_kernel<<<nb, 256, 0, stream>>>(CNT, BSUM, N);
    scan2_kernel<<<1, 256, 0, stream>>>(BSUM, nb);
    scan3_kernel<<<nb, 256, 0, stream>>>(CNT, BSUM, ROFF, N);
    scatter_kernel<<<eb, 256, 0, stream>>>(esrc, edst, ew, ROFF, CUR, CDST, CW, E);

    dim3 gg(2, (N + 127) / 128);
    gemm_xw_kernel<<<gg, 256, 0, stream>>>(feat, WT, XWs, N);
    gemm_xw_kernel<<<gg, 256, 0, stream>>>(faug, WT, XWt, N);

    spmm_h2_kernel<<<(N + 3) / 4, 256, 0, stream>>>(XWs, XWt, ROFF, CDST, CW, b1, Gs, Gt, N);

    int nw = (N + 15) / 16;
    gemm_k2_kernel<<<(nw + 3) / 4, 256, 0, stream>>>(Gs, Gt, WsT, WtT, GSp, N);

    spmm_k2_kernel<<<1024, 256, 0, stream>>>(GSp, ROFF, CDST, CW, bsv, btv,
                                             DEG, ASG_S, RED, N);

    edge_trace_kernel<<<256, 256, 0, stream>>>(esrc, edst, ASG_S, RED, E);
    finalize_kernel<<<1, 1, 0, stream>>>(RED, (float*)d_out, N, E);
}

// Round 7
// 355.824 us; speedup vs baseline: 2.5541x; 1.1388x over previous
//
#include <hip/hip_runtime.h>
#include <math.h>

constexpr int Fdim = 256;
constexpr int Hdim = 256;
constexpr int Kc   = 16;

constexpr int RSTRIDE = 32;
constexpr int NRED    = 34;   // 0..15 nl, 16..31 cluster_sizes, 32 con, 33 trace

typedef __attribute__((ext_vector_type(8))) short s8v;   // 8 bf16 (4 VGPRs)
typedef __attribute__((ext_vector_type(4))) float f4v;   // 4 fp32 acc

__device__ __forceinline__ float selu1(float x){
    const float scale = 1.0507009873554805f;
    const float alpha = 1.6732632423543772f;
    return scale * (x > 0.f ? x : alpha * expm1f(x));
}

__device__ __forceinline__ ushort f2bf(float x){
    union { float f; unsigned u; } c; c.f = x;
    unsigned r = c.u + 0x7fffu + ((c.u >> 16) & 1u);   // RNE
    return (ushort)(r >> 16);
}

__device__ __forceinline__ float bf2f(ushort b){
    union { unsigned u; float f; } c; c.u = ((unsigned)b) << 16;
    return c.f;
}

__device__ __forceinline__ float bflo(unsigned v){
    union { unsigned u; float f; } c; c.u = v << 16; return c.f;
}
__device__ __forceinline__ float bfhi(unsigned v){
    union { unsigned u; float f; } c; c.u = v & 0xffff0000u; return c.f;
}

// fp8 e4m3 encode via HW converter (RNE)
__device__ __forceinline__ unsigned char f2fp8(float x){
    int v = __builtin_amdgcn_cvt_pk_fp8_f32(x, x, 0, false);
    return (unsigned char)(v & 0xff);
}

// ---------------- CSR build ----------------
__global__ void hist_kernel(const int* __restrict__ src, const int* __restrict__ dst,
                            int* __restrict__ scnt, int* __restrict__ dcnt, int E){
    int i = blockIdx.x * blockDim.x + threadIdx.x;
    if (i < E){
        atomicAdd(&scnt[src[i]], 1);
        atomicAdd(&dcnt[dst[i]], 1);
    }
}

// hierarchical scan
__global__ __launch_bounds__(256) void scan1_kernel(const int* __restrict__ cnt,
                                                    int* __restrict__ bsum, int n){
    int i = blockIdx.x * 256 + threadIdx.x;
    int v = (i < n) ? cnt[i] : 0;
    #pragma unroll
    for (int off = 1; off < 64; off <<= 1) v += __shfl_xor(v, off);
    __shared__ int sdata[4];
    int wid = threadIdx.x >> 6, lane = threadIdx.x & 63;
    if (lane == 0) sdata[wid] = v;
    __syncthreads();
    if (threadIdx.x == 0) bsum[blockIdx.x] = sdata[0] + sdata[1] + sdata[2] + sdata[3];
}

__global__ __launch_bounds__(256) void scan2_kernel(int* __restrict__ bsum, int nb){
    __shared__ int s[256];
    int t = threadIdx.x;
    int v = (t < nb) ? bsum[t] : 0;
    s[t] = v;
    __syncthreads();
    for (int off = 1; off < 256; off <<= 1){
        int x = (t >= off) ? s[t - off] : 0;
        __syncthreads();
        s[t] += x;
        __syncthreads();
    }
    if (t < nb) bsum[t] = s[t] - v;   // exclusive
}

__global__ __launch_bounds__(256) void scan3_kernel(const int* __restrict__ cnt,
        const int* __restrict__ bsum, int* __restrict__ roff, int n){
    __shared__ int ls[256];
    int t = threadIdx.x;
    int i = blockIdx.x * 256 + t;
    int v = (i < n) ? cnt[i] : 0;
    ls[t] = v;
    __syncthreads();
    for (int off = 1; off < 256; off <<= 1){
        int x = (t >= off) ? ls[t - off] : 0;
        __syncthreads();
        ls[t] += x;
        __syncthreads();
    }
    int base = bsum[blockIdx.x];
    if (i < n)  roff[i] = base + ls[t] - v;
    if (i == n - 1) roff[n] = base + ls[t];
}

__global__ void scatter_kernel(const int* __restrict__ src, const int* __restrict__ dst,
                               const float* __restrict__ w, const int* __restrict__ roff,
                               int* __restrict__ cur, int* __restrict__ cdst,
                               float* __restrict__ cw, int E){
    int i = blockIdx.x * blockDim.x + threadIdx.x;
    if (i < E){
        int s = src[i];
        int p = roff[s] + atomicAdd(&cur[s], 1);
        cdst[p] = dst[i];
        cw[p]   = w[i];
    }
}

// ---------------- W1 transpose-cast: Wt[n][k] = bf16(W1[k][n]) ----------------
__global__ void castw_kernel(const float* __restrict__ W, ushort* __restrict__ Wt){
    __shared__ float t[16][17];
    int tx = threadIdx.x, ty = threadIdx.y;
    int k  = blockIdx.y * 16 + ty;
    int nn = blockIdx.x * 16 + tx;
    t[ty][tx] = W[k * 256 + nn];
    __syncthreads();
    int n2 = blockIdx.x * 16 + ty;
    int k2 = blockIdx.y * 16 + tx;
    Wt[n2 * 256 + k2] = f2bf(t[tx][ty]);
}

// ---------------- Ws/Wt transpose-cast ----------------
__global__ void castwk_kernel(const float* __restrict__ Ws, const float* __restrict__ Wt,
                              ushort* __restrict__ WsT, ushort* __restrict__ WtT){
    int h = threadIdx.x;   // 0..255
    #pragma unroll
    for (int c = 0; c < 16; ++c){
        WsT[c * 256 + h] = f2bf(Ws[h * 16 + c]);
        WtT[c * 256 + h] = f2bf(Wt[h * 16 + c]);
    }
}

// ---------------- MFMA bf16 GEMM: XWp_fp8[M][512B] (half sel) = A_f32 @ W ----------
__global__ __launch_bounds__(256, 2) void gemm_xw_kernel(
        const float* __restrict__ A, const ushort* __restrict__ Bt,
        unsigned char* __restrict__ C8, int M, int halfoff){
    __shared__ ushort blds[32768];
    int tid = threadIdx.x;
    int n0  = blockIdx.x * 128;
    int bm  = blockIdx.y * 128;

    #pragma unroll
    for (int j = 0; j < 16; ++j){
        int c  = j * 256 + tid;
        int nl = c >> 5, kc = c & 31;
        uint4 v = *reinterpret_cast<const uint4*>(Bt + (((size_t)(n0 + nl)) << 8) + (kc << 3));
        unsigned boff = (unsigned)(((nl << 9) + (kc << 4)) ^ ((nl & 7) << 4));
        *reinterpret_cast<uint4*>(reinterpret_cast<char*>(blds) + boff) = v;
    }
    __syncthreads();

    int w = tid >> 6, l = tid & 63;
    int lr = l & 15, lk = l >> 4;

    f4v acc[2][8];
    #pragma unroll
    for (int m = 0; m < 2; ++m)
        #pragma unroll
        for (int t = 0; t < 8; ++t)
            acc[m][t] = (f4v){0.f, 0.f, 0.f, 0.f};

    int r0 = bm + w * 32 + lr;
    int r1 = r0 + 16;
    int rc0 = min(r0, M - 1), rc1 = min(r1, M - 1);
    const float* a0 = A + (size_t)rc0 * 256 + lk * 8;
    const float* a1 = A + (size_t)rc1 * 256 + lk * 8;

    for (int ks = 0; ks < 8; ++ks){
        s8v af0, af1;
        {
            float4 f0 = *reinterpret_cast<const float4*>(a0 + ks * 32);
            float4 f1 = *reinterpret_cast<const float4*>(a0 + ks * 32 + 4);
            af0[0] = (short)f2bf(f0.x); af0[1] = (short)f2bf(f0.y);
            af0[2] = (short)f2bf(f0.z); af0[3] = (short)f2bf(f0.w);
            af0[4] = (short)f2bf(f1.x); af0[5] = (short)f2bf(f1.y);
            af0[6] = (short)f2bf(f1.z); af0[7] = (short)f2bf(f1.w);
        }
        {
            float4 f0 = *reinterpret_cast<const float4*>(a1 + ks * 32);
            float4 f1 = *reinterpret_cast<const float4*>(a1 + ks * 32 + 4);
            af1[0] = (short)f2bf(f0.x); af1[1] = (short)f2bf(f0.y);
            af1[2] = (short)f2bf(f0.z); af1[3] = (short)f2bf(f0.w);
            af1[4] = (short)f2bf(f1.x); af1[5] = (short)f2bf(f1.y);
            af1[6] = (short)f2bf(f1.z); af1[7] = (short)f2bf(f1.w);
        }
        #pragma unroll
        for (int t = 0; t < 8; ++t){
            int nl = t * 16 + lr;
            unsigned boff = (unsigned)(((nl << 9) + ((ks * 4 + lk) << 4)) ^ ((nl & 7) << 4));
            s8v bf = *reinterpret_cast<const s8v*>(reinterpret_cast<const char*>(blds) + boff);
            acc[0][t] = __builtin_amdgcn_mfma_f32_16x16x32_bf16(af0, bf, acc[0][t], 0, 0, 0);
            acc[1][t] = __builtin_amdgcn_mfma_f32_16x16x32_bf16(af1, bf, acc[1][t], 0, 0, 0);
        }
    }

    // fp8 store: byte addr = row*512 + halfoff + col
    #pragma unroll
    for (int m = 0; m < 2; ++m){
        #pragma unroll
        for (int t = 0; t < 8; ++t){
            int col = n0 + t * 16 + lr;
            #pragma unroll
            for (int j = 0; j < 4; ++j){
                int row = bm + w * 32 + m * 16 + lk * 4 + j;
                if (row < M) C8[(size_t)row * 512 + halfoff + col] = f2fp8(acc[m][t][j]);
            }
        }
    }
}

// ---------------- fused SPMM over H=256 (student+teacher), fp8 table, + bias + selu ----
// one wave per row; lane covers 8 fp8 cols (8B load); lanes 0-31 student, 32-63 teacher.
__global__ __launch_bounds__(256) void spmm_h2_kernel(
        const unsigned char* __restrict__ XWp,
        const int* __restrict__ roff, const int* __restrict__ cdst,
        const float* __restrict__ cw, const float* __restrict__ b1,
        ushort* __restrict__ Gs, ushort* __restrict__ Gt, int n){
    int wid = threadIdx.x >> 6, lane = threadIdx.x & 63;
    int r = blockIdx.x * 4 + wid;
    if (r >= n) return;
    int half = lane >> 5;          // 0 = student, 1 = teacher
    int hl   = lane & 31;          // col group: cols hl*8 .. hl*8+7
    const unsigned char* base = XWp + lane * 8;
    int e0 = roff[r], e1 = roff[r + 1];
    float acc[8] = {};

    #define ACCUM8(V, W) do{                                                      \
        auto fa_ = __builtin_amdgcn_cvt_pk_f32_fp8((V).x, false);                 \
        acc[0] = fmaf((W), fa_[0], acc[0]); acc[1] = fmaf((W), fa_[1], acc[1]);   \
        auto fb_ = __builtin_amdgcn_cvt_pk_f32_fp8((V).x, true);                  \
        acc[2] = fmaf((W), fb_[0], acc[2]); acc[3] = fmaf((W), fb_[1], acc[3]);   \
        auto fc_ = __builtin_amdgcn_cvt_pk_f32_fp8((V).y, false);                 \
        acc[4] = fmaf((W), fc_[0], acc[4]); acc[5] = fmaf((W), fc_[1], acc[5]);   \
        auto fd_ = __builtin_amdgcn_cvt_pk_f32_fp8((V).y, true);                  \
        acc[6] = fmaf((W), fd_[0], acc[6]); acc[7] = fmaf((W), fd_[1], acc[7]);   \
    }while(0)

    int e = e0;
    for (; e + 3 < e1; e += 4){
        int d0 = cdst[e],     d1 = cdst[e + 1];
        int d2 = cdst[e + 2], d3 = cdst[e + 3];
        float w0 = cw[e],     w1 = cw[e + 1];
        float w2 = cw[e + 2], w3 = cw[e + 3];
        uint2 v0 = *reinterpret_cast<const uint2*>(base + ((size_t)d0 << 9));
        uint2 v1 = *reinterpret_cast<const uint2*>(base + ((size_t)d1 << 9));
        uint2 v2 = *reinterpret_cast<const uint2*>(base + ((size_t)d2 << 9));
        uint2 v3 = *reinterpret_cast<const uint2*>(base + ((size_t)d3 << 9));
        ACCUM8(v0, w0); ACCUM8(v1, w1); ACCUM8(v2, w2); ACCUM8(v3, w3);
    }
    for (; e < e1; ++e){
        int d   = cdst[e];
        float w = cw[e];
        uint2 v = *reinterpret_cast<const uint2*>(base + ((size_t)d << 9));
        ACCUM8(v, w);
    }
    #undef ACCUM8

    const float* bp = b1 + hl * 8;
    float4 bb0 = *reinterpret_cast<const float4*>(bp);
    float4 bb1 = *reinterpret_cast<const float4*>(bp + 4);
    float bv[8] = {bb0.x, bb0.y, bb0.z, bb0.w, bb1.x, bb1.y, bb1.z, bb1.w};
    ushort o[8];
    #pragma unroll
    for (int q = 0; q < 8; ++q) o[q] = f2bf(selu1(acc[q] + bv[q]));
    uint4 ov = *reinterpret_cast<const uint4*>(o);
    ushort* gout = (half ? Gt : Gs) + (size_t)r * Hdim + hl * 8;
    *reinterpret_cast<uint4*>(gout) = ov;
}

// ---------------- fused MFMA: GS = pack(Gs@Ws, Gt@Wt) bf16   [N,256]x[256,16] ----------
__global__ __launch_bounds__(256) void gemm_k2_kernel(
        const ushort* __restrict__ Gs, const ushort* __restrict__ Gt,
        const ushort* __restrict__ WsT, const ushort* __restrict__ WtT,
        unsigned* __restrict__ GSp, int n){
    int wv = blockIdx.x * 4 + (threadIdx.x >> 6);
    int l  = threadIdx.x & 63;
    int lr = l & 15, lk = l >> 4;
    int nw = (n + 15) >> 4;
    if (wv >= nw) return;
    int r0 = wv * 16;

    s8v bs_[8], bt_[8];
    #pragma unroll
    for (int ks = 0; ks < 8; ++ks){
        bs_[ks] = *reinterpret_cast<const s8v*>(WsT + lr * 256 + ks * 32 + lk * 8);
        bt_[ks] = *reinterpret_cast<const s8v*>(WtT + lr * 256 + ks * 32 + lk * 8);
    }

    f4v accs = (f4v){0.f,0.f,0.f,0.f}, acct = (f4v){0.f,0.f,0.f,0.f};
    int row = min(r0 + lr, n - 1);
    const ushort* gsrow = Gs + (size_t)row * 256 + lk * 8;
    const ushort* gtrow = Gt + (size_t)row * 256 + lk * 8;
    #pragma unroll
    for (int ks = 0; ks < 8; ++ks){
        s8v a_s = *reinterpret_cast<const s8v*>(gsrow + ks * 32);
        s8v a_t = *reinterpret_cast<const s8v*>(gtrow + ks * 32);
        accs = __builtin_amdgcn_mfma_f32_16x16x32_bf16(a_s, bs_[ks], accs, 0, 0, 0);
        acct = __builtin_amdgcn_mfma_f32_16x16x32_bf16(a_t, bt_[ks], acct, 0, 0, 0);
    }
    #pragma unroll
    for (int j = 0; j < 4; ++j){
        int rr = r0 + lk * 4 + j;
        if (rr < n){
            unsigned pv = (unsigned)f2bf(accs[j]) | ((unsigned)f2bf(acct[j]) << 16);
            GSp[(size_t)rr * 16 + lr] = pv;
        }
    }
}

// ---------------- fused: SPMM-K + softmax (both branches) + node stats ----------------
// one wave per row; 4 edge slots x 16 cluster lanes; grid-stride over rows.
__global__ __launch_bounds__(256) void spmm_k2_kernel(
        const unsigned* __restrict__ GSp,
        const int* __restrict__ roff, const int* __restrict__ cdst,
        const float* __restrict__ cw, const float* __restrict__ bsv,
        const float* __restrict__ btv, const int* __restrict__ deg,
        float* __restrict__ asg, float* __restrict__ red, int n){
    int tid  = threadIdx.x;
    int wid  = tid >> 6, lane = tid & 63;
    int slot = lane >> 4, j = lane & 15;
    float bs_ = bsv[j], bt_ = btv[j];
    float nl_l = 0.f, cs_l = 0.f, con_l = 0.f;

    int rstride = gridDim.x * 4;
    for (int r = blockIdx.x * 4 + wid; r < n; r += rstride){
        int e0 = roff[r], e1 = roff[r + 1];
        float as_ = 0.f, at_ = 0.f;
        for (int e = e0 + slot; e < e1; e += 4){
            int d   = cdst[e];
            float w = cw[e];
            unsigned v = GSp[(size_t)d * 16 + j];
            as_ = fmaf(w, bflo(v), as_);
            at_ = fmaf(w, bfhi(v), at_);
        }
        // combine 4 slots -> all lanes hold the full row sum
        as_ += __shfl_xor(as_, 16); as_ += __shfl_xor(as_, 32);
        at_ += __shfl_xor(at_, 16); at_ += __shfl_xor(at_, 32);
        float xs = selu1(as_ + bs_);
        float xt = selu1(at_ + bt_);
        float ms = xs, mt = xt;
        #pragma unroll
        for (int off = 8; off >= 1; off >>= 1){
            ms = fmaxf(ms, __shfl_xor(ms, off));
            mt = fmaxf(mt, __shfl_xor(mt, off));
        }
        float es = expf(xs - ms), et = expf(xt - mt);
        float ss = es, st = et;
        #pragma unroll
        for (int off = 8; off >= 1; off >>= 1){
            ss += __shfl_xor(ss, off);
            st += __shfl_xor(st, off);
        }
        float a = es / ss, b = et / st;
        if (slot == 0) asg[(size_t)r * 16 + j] = a;
        float dgr = (float)deg[r];
        nl_l += a * dgr;
        cs_l += a;
        float dot = a * b, na = a * a, nb = b * b;
        #pragma unroll
        for (int off = 8; off >= 1; off >>= 1){
            dot += __shfl_xor(dot, off);
            na  += __shfl_xor(na, off);
            nb  += __shfl_xor(nb, off);
        }
        if (j == 0){
            na = fmaxf(sqrtf(na), 1e-12f);
            nb = fmaxf(sqrtf(nb), 1e-12f);
            con_l += 2.f - 2.f * dot / (na * nb);
        }
    }

    // slots hold exact duplicates -> combine then scale by 1/4
    nl_l  += __shfl_xor(nl_l, 16);  nl_l  += __shfl_xor(nl_l, 32);  nl_l  *= 0.25f;
    cs_l  += __shfl_xor(cs_l, 16);  cs_l  += __shfl_xor(cs_l, 32);  cs_l  *= 0.25f;
    con_l += __shfl_xor(con_l, 16); con_l += __shfl_xor(con_l, 32); con_l *= 0.25f;

    __shared__ float part[4][33];
    if (lane < 16){
        part[wid][lane]      = nl_l;
        part[wid][16 + lane] = cs_l;
    }
    if (lane == 0) part[wid][32] = con_l;
    __syncthreads();
    if (tid < 33){
        float s = part[0][tid] + part[1][tid] + part[2][tid] + part[3][tid];
        atomicAdd(&red[tid * RSTRIDE], s);
    }
}

// ---------------- per-edge trace: sum_e dot(S[src], S[dst]) ----------------
__global__ __launch_bounds__(256) void edge_trace_kernel(const int* __restrict__ src,
        const int* __restrict__ dst, const float* __restrict__ as_,
        float* __restrict__ red, int E){
    int tid    = blockIdx.x * blockDim.x + threadIdx.x;
    int stride = gridDim.x * blockDim.x;
    float dot = 0.f;
    for (int i = tid; i < E; i += stride){
        const float4* pa = reinterpret_cast<const float4*>(as_ + (size_t)src[i] * 16);
        const float4* pb = reinterpret_cast<const float4*>(as_ + (size_t)dst[i] * 16);
        #pragma unroll
        for (int q = 0; q < 4; ++q){
            float4 va = pa[q]; float4 vb = pb[q];
            dot = fmaf(va.x, vb.x, dot); dot = fmaf(va.y, vb.y, dot);
            dot = fmaf(va.z, vb.z, dot); dot = fmaf(va.w, vb.w, dot);
        }
    }
    #pragma unroll
    for (int off = 1; off < 64; off <<= 1) dot += __shfl_xor(dot, off);
    __shared__ float part[4];
    int wid = threadIdx.x >> 6, lane = threadIdx.x & 63;
    if (lane == 0) part[wid] = dot;
    __syncthreads();
    if (threadIdx.x == 0)
        atomicAdd(&red[33 * RSTRIDE], part[0] + part[1] + part[2] + part[3]);
}

// ---------------- finalize ----------------
__global__ void finalize_kernel(const float* __restrict__ red, float* __restrict__ out,
                                int n, int E){
    float trace = red[33 * RSTRIDE];
    float nl2 = 0.f, cs2 = 0.f;
    #pragma unroll
    for (int k = 0; k < 16; ++k){
        nl2 = fmaf(red[k * RSTRIDE],        red[k * RSTRIDE],        nl2);
        cs2 = fmaf(red[(16 + k) * RSTRIDE], red[(16 + k) * RSTRIDE], cs2);
    }
    float twoE = 2.f * (float)E;
    float spectral = -(trace - nl2 / twoE) / twoE;
    float cluster  = sqrtf(cs2) / (float)n * 4.f - 1.f;
    float con      = red[32 * RSTRIDE] / (float)n;
    out[0] = spectral + cluster + con;
}

extern "C" void kernel_launch(void* const* d_in, const int* in_sizes, int n_in,
                              void* d_out, int out_size, void* d_ws, size_t ws_size,
                              hipStream_t stream){
    const int*   esrc = (const int*)d_in[0];
    const int*   edst = (const int*)d_in[1];
    const float* ew   = (const float*)d_in[2];
    const float* feat = (const float*)d_in[3];
    const float* faug = (const float*)d_in[4];
    const float* W1   = (const float*)d_in[5];
    const float* b1   = (const float*)d_in[6];
    const float* Wsm  = (const float*)d_in[7];
    const float* bsv  = (const float*)d_in[8];
    const float* Wtm  = (const float*)d_in[9];
    const float* btv  = (const float*)d_in[10];
    int E = in_sizes[0];
    int N = in_sizes[3] / Fdim;

    char* ws = (char*)d_ws;
    size_t off = 0;
    auto alloc = [&](size_t bytes) -> char* {
        char* p = ws + off;
        off = (off + bytes + 255) & ~(size_t)255;
        return p;
    };
    unsigned char* XWp = (unsigned char*)alloc((size_t)N * 512);  // fp8 [N][512B]
    ushort*   Gs    = (ushort*)alloc((size_t)N * Hdim * 2);
    ushort*   Gt    = (ushort*)alloc((size_t)N * Hdim * 2);
    unsigned* GSp   = (unsigned*)alloc((size_t)N * Kc * 4);
    float*    ASG_S = (float*)alloc((size_t)N * Kc * 4);
    ushort*   WT    = (ushort*)alloc((size_t)256 * 256 * 2);
    ushort*   WsT   = (ushort*)alloc((size_t)16 * 256 * 2);
    ushort*   WtT   = (ushort*)alloc((size_t)16 * 256 * 2);
    int*      ROFF  = (int*)alloc((size_t)(N + 1) * 4);
    int*      CNT   = (int*)alloc((size_t)N * 4);
    int*      CUR   = (int*)alloc((size_t)N * 4);
    int*      DEG   = (int*)alloc((size_t)N * 4);
    int*      BSUM  = (int*)alloc((size_t)256 * 4);
    int*      CDST  = (int*)alloc((size_t)E * 4);
    float*    CW    = (float*)alloc((size_t)E * 4);
    float*    RED   = (float*)alloc((size_t)NRED * RSTRIDE * 4);

    hipMemsetAsync(CNT, 0, (size_t)N * 4, stream);
    hipMemsetAsync(CUR, 0, (size_t)N * 4, stream);
    hipMemsetAsync(DEG, 0, (size_t)N * 4, stream);
    hipMemsetAsync(RED, 0, (size_t)NRED * RSTRIDE * 4, stream);

    int eb = (E + 255) / 256;
    int nb = (N + 255) / 256;
    castw_kernel<<<dim3(16, 16), dim3(16, 16), 0, stream>>>(W1, WT);
    castwk_kernel<<<1, 256, 0, stream>>>(Wsm, Wtm, WsT, WtT);
    hist_kernel<<<eb, 256, 0, stream>>>(esrc, edst, CNT, DEG, E);
    scan1_kernel<<<nb, 256, 0, stream>>>(CNT, BSUM, N);
    scan2_kernel<<<1, 256, 0, stream>>>(BSUM, nb);
    scan3_kernel<<<nb, 256, 0, stream>>>(CNT, BSUM, ROFF, N);
    scatter_kernel<<<eb, 256, 0, stream>>>(esrc, edst, ew, ROFF, CUR, CDST, CW, E);

    dim3 gg(2, (N + 127) / 128);
    gemm_xw_kernel<<<gg, 256, 0, stream>>>(feat, WT, XWp, N, 0);
    gemm_xw_kernel<<<gg, 256, 0, stream>>>(faug, WT, XWp, N, 256);

    spmm_h2_kernel<<<(N + 3) / 4, 256, 0, stream>>>(XWp, ROFF, CDST, CW, b1, Gs, Gt, N);

    int nw = (N + 15) / 16;
    gemm_k2_kernel<<<(nw + 3) / 4, 256, 0, stream>>>(Gs, Gt, WsT, WtT, GSp, N);

    spmm_k2_kernel<<<2048, 256, 0, stream>>>(GSp, ROFF, CDST, CW, bsv, btv,
                                             DEG, ASG_S, RED, N);

    edge_trace_kernel<<<256, 256, 0, stream>>>(esrc, edst, ASG_S, RED, E);
    finalize_kernel<<<1, 1, 0, stream>>>(RED, (float*)d_out, N, E);
}

// Round 8
// 349.254 us; speedup vs baseline: 2.6021x; 1.0188x over previous
//
#include <hip/hip_runtime.h>
#include <math.h>

constexpr int Fdim = 256;
constexpr int Hdim = 256;
constexpr int Kc   = 16;

constexpr int RSTRIDE = 32;
constexpr int NRED    = 34;   // 0..15 nl, 16..31 cluster_sizes, 32 con, 33 trace
constexpr int BCAP    = 5120; // bucket capacity (mean 4096, 16 sigma slack)

typedef __attribute__((ext_vector_type(8))) short s8v;   // 8 bf16 (4 VGPRs)
typedef __attribute__((ext_vector_type(4))) float f4v;   // 4 fp32 acc

__device__ __forceinline__ float selu1(float x){
    const float scale = 1.0507009873554805f;
    const float alpha = 1.6732632423543772f;
    return scale * (x > 0.f ? x : alpha * expm1f(x));
}

__device__ __forceinline__ ushort f2bf(float x){
    union { float f; unsigned u; } c; c.f = x;
    unsigned r = c.u + 0x7fffu + ((c.u >> 16) & 1u);   // RNE
    return (ushort)(r >> 16);
}

__device__ __forceinline__ float bf2f(ushort b){
    union { unsigned u; float f; } c; c.u = ((unsigned)b) << 16;
    return c.f;
}

__device__ __forceinline__ float bflo(unsigned v){
    union { unsigned u; float f; } c; c.u = v << 16; return c.f;
}
__device__ __forceinline__ float bfhi(unsigned v){
    union { unsigned u; float f; } c; c.u = v & 0xffff0000u; return c.f;
}

// fp8 e4m3 encode via HW converter (RNE)
__device__ __forceinline__ unsigned char f2fp8(float x){
    int v = __builtin_amdgcn_cvt_pk_fp8_f32(x, x, 0, false);
    return (unsigned char)(v & 0xff);
}

// ---------------- CSR build: phase A = hist + bucket append ----------------
__global__ __launch_bounds__(256) void hist_bucket_kernel(
        const int* __restrict__ src, const int* __restrict__ dst,
        const float* __restrict__ w,
        int* __restrict__ scnt, int* __restrict__ dcnt, int* __restrict__ bcnt,
        int* __restrict__ bsrc, int* __restrict__ bdst, float* __restrict__ bw, int E){
    int i = blockIdx.x * blockDim.x + threadIdx.x;
    if (i >= E) return;
    int s = src[i], d = dst[i];
    float wv = w[i];
    atomicAdd(&scnt[s], 1);
    atomicAdd(&dcnt[d], 1);
    int b = s >> 8;
    int p = atomicAdd(&bcnt[b * 32], 1);
    if (p < BCAP){
        int g = b * BCAP + p;
        bsrc[g] = s; bdst[g] = d; bw[g] = wv;
    }
}

// hierarchical scan
__global__ __launch_bounds__(256) void scan1_kernel(const int* __restrict__ cnt,
                                                    int* __restrict__ bsum, int n){
    int i = blockIdx.x * 256 + threadIdx.x;
    int v = (i < n) ? cnt[i] : 0;
    #pragma unroll
    for (int off = 1; off < 64; off <<= 1) v += __shfl_xor(v, off);
    __shared__ int sdata[4];
    int wid = threadIdx.x >> 6, lane = threadIdx.x & 63;
    if (lane == 0) sdata[wid] = v;
    __syncthreads();
    if (threadIdx.x == 0) bsum[blockIdx.x] = sdata[0] + sdata[1] + sdata[2] + sdata[3];
}

__global__ __launch_bounds__(256) void scan2_kernel(int* __restrict__ bsum, int nb){
    __shared__ int s[256];
    int t = threadIdx.x;
    int v = (t < nb) ? bsum[t] : 0;
    s[t] = v;
    __syncthreads();
    for (int off = 1; off < 256; off <<= 1){
        int x = (t >= off) ? s[t - off] : 0;
        __syncthreads();
        s[t] += x;
        __syncthreads();
    }
    if (t < nb) bsum[t] = s[t] - v;   // exclusive
}

__global__ __launch_bounds__(256) void scan3_kernel(const int* __restrict__ cnt,
        const int* __restrict__ bsum, int* __restrict__ roff, int n){
    __shared__ int ls[256];
    int t = threadIdx.x;
    int i = blockIdx.x * 256 + t;
    int v = (i < n) ? cnt[i] : 0;
    ls[t] = v;
    __syncthreads();
    for (int off = 1; off < 256; off <<= 1){
        int x = (t >= off) ? ls[t - off] : 0;
        __syncthreads();
        ls[t] += x;
        __syncthreads();
    }
    int base = bsum[blockIdx.x];
    if (i < n)  roff[i] = base + ls[t] - v;
    if (i == n - 1) roff[n] = base + ls[t];
}

// ---------------- CSR build: phase B = bucket-local scatter (LDS cursors) ----------
__global__ __launch_bounds__(256) void bucket_scatter_kernel(
        const int* __restrict__ bcnt, const int* __restrict__ bsrc,
        const int* __restrict__ bdst, const float* __restrict__ bw,
        const int* __restrict__ roff, uint2* __restrict__ csr){
    __shared__ int cur[256];
    int b = blockIdx.x;
    cur[threadIdx.x] = 0;
    __syncthreads();
    int cnt = min(bcnt[b * 32], BCAP);
    for (int t = threadIdx.x; t < cnt; t += 256){
        int g = b * BCAP + t;
        int s = bsrc[g];
        int p = roff[s] + atomicAdd(&cur[s & 255], 1);
        csr[p] = make_uint2((unsigned)bdst[g], __float_as_uint(bw[g]));
    }
}

// ---------------- W1 transpose-cast: Wt[n][k] = bf16(W1[k][n]) ----------------
__global__ void castw_kernel(const float* __restrict__ W, ushort* __restrict__ Wt){
    __shared__ float t[16][17];
    int tx = threadIdx.x, ty = threadIdx.y;
    int k  = blockIdx.y * 16 + ty;
    int nn = blockIdx.x * 16 + tx;
    t[ty][tx] = W[k * 256 + nn];
    __syncthreads();
    int n2 = blockIdx.x * 16 + ty;
    int k2 = blockIdx.y * 16 + tx;
    Wt[n2 * 256 + k2] = f2bf(t[tx][ty]);
}

// ---------------- Ws/Wt transpose-cast ----------------
__global__ void castwk_kernel(const float* __restrict__ Ws, const float* __restrict__ Wt,
                              ushort* __restrict__ WsT, ushort* __restrict__ WtT){
    int h = threadIdx.x;   // 0..255
    #pragma unroll
    for (int c = 0; c < 16; ++c){
        WsT[c * 256 + h] = f2bf(Ws[h * 16 + c]);
        WtT[c * 256 + h] = f2bf(Wt[h * 16 + c]);
    }
}

// ---------------- MFMA bf16 GEMM: XWp_fp8[M][512B] (half sel) = A_f32 @ W ----------
__global__ __launch_bounds__(256, 2) void gemm_xw_kernel(
        const float* __restrict__ A, const ushort* __restrict__ Bt,
        unsigned char* __restrict__ C8, int M, int halfoff){
    __shared__ ushort blds[32768];
    int tid = threadIdx.x;
    int n0  = blockIdx.x * 128;
    int bm  = blockIdx.y * 128;

    #pragma unroll
    for (int j = 0; j < 16; ++j){
        int c  = j * 256 + tid;
        int nl = c >> 5, kc = c & 31;
        uint4 v = *reinterpret_cast<const uint4*>(Bt + (((size_t)(n0 + nl)) << 8) + (kc << 3));
        unsigned boff = (unsigned)(((nl << 9) + (kc << 4)) ^ ((nl & 7) << 4));
        *reinterpret_cast<uint4*>(reinterpret_cast<char*>(blds) + boff) = v;
    }
    __syncthreads();

    int w = tid >> 6, l = tid & 63;
    int lr = l & 15, lk = l >> 4;

    f4v acc[2][8];
    #pragma unroll
    for (int m = 0; m < 2; ++m)
        #pragma unroll
        for (int t = 0; t < 8; ++t)
            acc[m][t] = (f4v){0.f, 0.f, 0.f, 0.f};

    int r0 = bm + w * 32 + lr;
    int r1 = r0 + 16;
    int rc0 = min(r0, M - 1), rc1 = min(r1, M - 1);
    const float* a0 = A + (size_t)rc0 * 256 + lk * 8;
    const float* a1 = A + (size_t)rc1 * 256 + lk * 8;

    for (int ks = 0; ks < 8; ++ks){
        s8v af0, af1;
        {
            float4 f0 = *reinterpret_cast<const float4*>(a0 + ks * 32);
            float4 f1 = *reinterpret_cast<const float4*>(a0 + ks * 32 + 4);
            af0[0] = (short)f2bf(f0.x); af0[1] = (short)f2bf(f0.y);
            af0[2] = (short)f2bf(f0.z); af0[3] = (short)f2bf(f0.w);
            af0[4] = (short)f2bf(f1.x); af0[5] = (short)f2bf(f1.y);
            af0[6] = (short)f2bf(f1.z); af0[7] = (short)f2bf(f1.w);
        }
        {
            float4 f0 = *reinterpret_cast<const float4*>(a1 + ks * 32);
            float4 f1 = *reinterpret_cast<const float4*>(a1 + ks * 32 + 4);
            af1[0] = (short)f2bf(f0.x); af1[1] = (short)f2bf(f0.y);
            af1[2] = (short)f2bf(f0.z); af1[3] = (short)f2bf(f0.w);
            af1[4] = (short)f2bf(f1.x); af1[5] = (short)f2bf(f1.y);
            af1[6] = (short)f2bf(f1.z); af1[7] = (short)f2bf(f1.w);
        }
        #pragma unroll
        for (int t = 0; t < 8; ++t){
            int nl = t * 16 + lr;
            unsigned boff = (unsigned)(((nl << 9) + ((ks * 4 + lk) << 4)) ^ ((nl & 7) << 4));
            s8v bf = *reinterpret_cast<const s8v*>(reinterpret_cast<const char*>(blds) + boff);
            acc[0][t] = __builtin_amdgcn_mfma_f32_16x16x32_bf16(af0, bf, acc[0][t], 0, 0, 0);
            acc[1][t] = __builtin_amdgcn_mfma_f32_16x16x32_bf16(af1, bf, acc[1][t], 0, 0, 0);
        }
    }

    // fp8 store: byte addr = row*512 + halfoff + col
    #pragma unroll
    for (int m = 0; m < 2; ++m){
        #pragma unroll
        for (int t = 0; t < 8; ++t){
            int col = n0 + t * 16 + lr;
            #pragma unroll
            for (int j = 0; j < 4; ++j){
                int row = bm + w * 32 + m * 16 + lk * 4 + j;
                if (row < M) C8[(size_t)row * 512 + halfoff + col] = f2fp8(acc[m][t][j]);
            }
        }
    }
}

// ---------------- fused SPMM over H=256 (student+teacher), fp8 table, + bias + selu ----
__global__ __launch_bounds__(256) void spmm_h2_kernel(
        const unsigned char* __restrict__ XWp,
        const int* __restrict__ roff, const uint2* __restrict__ csr,
        const float* __restrict__ b1,
        ushort* __restrict__ Gs, ushort* __restrict__ Gt, int n){
    int wid = threadIdx.x >> 6, lane = threadIdx.x & 63;
    int r = blockIdx.x * 4 + wid;
    if (r >= n) return;
    int half = lane >> 5;          // 0 = student, 1 = teacher
    int hl   = lane & 31;          // col group: cols hl*8 .. hl*8+7
    const unsigned char* base = XWp + lane * 8;
    int e0 = roff[r], e1 = roff[r + 1];
    float acc[8] = {};

    #define ACCUM8(V, W) do{                                                      \
        auto fa_ = __builtin_amdgcn_cvt_pk_f32_fp8((V).x, false);                 \
        acc[0] = fmaf((W), fa_[0], acc[0]); acc[1] = fmaf((W), fa_[1], acc[1]);   \
        auto fb_ = __builtin_amdgcn_cvt_pk_f32_fp8((V).x, true);                  \
        acc[2] = fmaf((W), fb_[0], acc[2]); acc[3] = fmaf((W), fb_[1], acc[3]);   \
        auto fc_ = __builtin_amdgcn_cvt_pk_f32_fp8((V).y, false);                 \
        acc[4] = fmaf((W), fc_[0], acc[4]); acc[5] = fmaf((W), fc_[1], acc[5]);   \
        auto fd_ = __builtin_amdgcn_cvt_pk_f32_fp8((V).y, true);                  \
        acc[6] = fmaf((W), fd_[0], acc[6]); acc[7] = fmaf((W), fd_[1], acc[7]);   \
    }while(0)

    int e = e0;
    for (; e + 3 < e1; e += 4){
        uint2 c0 = csr[e],     c1 = csr[e + 1];
        uint2 c2 = csr[e + 2], c3 = csr[e + 3];
        float w0 = __uint_as_float(c0.y), w1 = __uint_as_float(c1.y);
        float w2 = __uint_as_float(c2.y), w3 = __uint_as_float(c3.y);
        uint2 v0 = *reinterpret_cast<const uint2*>(base + ((size_t)c0.x << 9));
        uint2 v1 = *reinterpret_cast<const uint2*>(base + ((size_t)c1.x << 9));
        uint2 v2 = *reinterpret_cast<const uint2*>(base + ((size_t)c2.x << 9));
        uint2 v3 = *reinterpret_cast<const uint2*>(base + ((size_t)c3.x << 9));
        ACCUM8(v0, w0); ACCUM8(v1, w1); ACCUM8(v2, w2); ACCUM8(v3, w3);
    }
    for (; e < e1; ++e){
        uint2 c = csr[e];
        float w = __uint_as_float(c.y);
        uint2 v = *reinterpret_cast<const uint2*>(base + ((size_t)c.x << 9));
        ACCUM8(v, w);
    }
    #undef ACCUM8

    const float* bp = b1 + hl * 8;
    float4 bb0 = *reinterpret_cast<const float4*>(bp);
    float4 bb1 = *reinterpret_cast<const float4*>(bp + 4);
    float bv[8] = {bb0.x, bb0.y, bb0.z, bb0.w, bb1.x, bb1.y, bb1.z, bb1.w};
    ushort o[8];
    #pragma unroll
    for (int q = 0; q < 8; ++q) o[q] = f2bf(selu1(acc[q] + bv[q]));
    uint4 ov = *reinterpret_cast<const uint4*>(o);
    ushort* gout = (half ? Gt : Gs) + (size_t)r * Hdim + hl * 8;
    *reinterpret_cast<uint4*>(gout) = ov;
}

// ---------------- fused MFMA: GS = pack(Gs@Ws, Gt@Wt) bf16   [N,256]x[256,16] ----------
__global__ __launch_bounds__(256) void gemm_k2_kernel(
        const ushort* __restrict__ Gs, const ushort* __restrict__ Gt,
        const ushort* __restrict__ WsT, const ushort* __restrict__ WtT,
        unsigned* __restrict__ GSp, int n){
    int wv = blockIdx.x * 4 + (threadIdx.x >> 6);
    int l  = threadIdx.x & 63;
    int lr = l & 15, lk = l >> 4;
    int nw = (n + 15) >> 4;
    if (wv >= nw) return;
    int r0 = wv * 16;

    s8v bs_[8], bt_[8];
    #pragma unroll
    for (int ks = 0; ks < 8; ++ks){
        bs_[ks] = *reinterpret_cast<const s8v*>(WsT + lr * 256 + ks * 32 + lk * 8);
        bt_[ks] = *reinterpret_cast<const s8v*>(WtT + lr * 256 + ks * 32 + lk * 8);
    }

    f4v accs = (f4v){0.f,0.f,0.f,0.f}, acct = (f4v){0.f,0.f,0.f,0.f};
    int row = min(r0 + lr, n - 1);
    const ushort* gsrow = Gs + (size_t)row * 256 + lk * 8;
    const ushort* gtrow = Gt + (size_t)row * 256 + lk * 8;
    #pragma unroll
    for (int ks = 0; ks < 8; ++ks){
        s8v a_s = *reinterpret_cast<const s8v*>(gsrow + ks * 32);
        s8v a_t = *reinterpret_cast<const s8v*>(gtrow + ks * 32);
        accs = __builtin_amdgcn_mfma_f32_16x16x32_bf16(a_s, bs_[ks], accs, 0, 0, 0);
        acct = __builtin_amdgcn_mfma_f32_16x16x32_bf16(a_t, bt_[ks], acct, 0, 0, 0);
    }
    #pragma unroll
    for (int j = 0; j < 4; ++j){
        int rr = r0 + lk * 4 + j;
        if (rr < n){
            unsigned pv = (unsigned)f2bf(accs[j]) | ((unsigned)f2bf(acct[j]) << 16);
            GSp[(size_t)rr * 16 + lr] = pv;
        }
    }
}

// ---------------- fused: SPMM-K + softmax (both branches) + node stats ----------------
__global__ __launch_bounds__(256) void spmm_k2_kernel(
        const unsigned* __restrict__ GSp,
        const int* __restrict__ roff, const uint2* __restrict__ csr,
        const float* __restrict__ bsv, const float* __restrict__ btv,
        const int* __restrict__ deg,
        float* __restrict__ asg, float* __restrict__ red, int n){
    int tid  = threadIdx.x;
    int wid  = tid >> 6, lane = tid & 63;
    int slot = lane >> 4, j = lane & 15;
    float bs_ = bsv[j], bt_ = btv[j];
    float nl_l = 0.f, cs_l = 0.f, con_l = 0.f;

    int rstride = gridDim.x * 4;
    for (int r = blockIdx.x * 4 + wid; r < n; r += rstride){
        int e0 = roff[r], e1 = roff[r + 1];
        float as_ = 0.f, at_ = 0.f;
        for (int e = e0 + slot; e < e1; e += 4){
            uint2 c = csr[e];
            float w = __uint_as_float(c.y);
            unsigned v = GSp[(size_t)c.x * 16 + j];
            as_ = fmaf(w, bflo(v), as_);
            at_ = fmaf(w, bfhi(v), at_);
        }
        as_ += __shfl_xor(as_, 16); as_ += __shfl_xor(as_, 32);
        at_ += __shfl_xor(at_, 16); at_ += __shfl_xor(at_, 32);
        float xs = selu1(as_ + bs_);
        float xt = selu1(at_ + bt_);
        float ms = xs, mt = xt;
        #pragma unroll
        for (int off = 8; off >= 1; off >>= 1){
            ms = fmaxf(ms, __shfl_xor(ms, off));
            mt = fmaxf(mt, __shfl_xor(mt, off));
        }
        float es = expf(xs - ms), et = expf(xt - mt);
        float ss = es, st = et;
        #pragma unroll
        for (int off = 8; off >= 1; off >>= 1){
            ss += __shfl_xor(ss, off);
            st += __shfl_xor(st, off);
        }
        float a = es / ss, b = et / st;
        if (slot == 0) asg[(size_t)r * 16 + j] = a;
        float dgr = (float)deg[r];
        nl_l += a * dgr;
        cs_l += a;
        float dot = a * b, na = a * a, nb = b * b;
        #pragma unroll
        for (int off = 8; off >= 1; off >>= 1){
            dot += __shfl_xor(dot, off);
            na  += __shfl_xor(na, off);
            nb  += __shfl_xor(nb, off);
        }
        if (j == 0){
            na = fmaxf(sqrtf(na), 1e-12f);
            nb = fmaxf(sqrtf(nb), 1e-12f);
            con_l += 2.f - 2.f * dot / (na * nb);
        }
    }

    // slots hold exact duplicates -> combine then scale by 1/4
    nl_l  += __shfl_xor(nl_l, 16);  nl_l  += __shfl_xor(nl_l, 32);  nl_l  *= 0.25f;
    cs_l  += __shfl_xor(cs_l, 16);  cs_l  += __shfl_xor(cs_l, 32);  cs_l  *= 0.25f;
    con_l += __shfl_xor(con_l, 16); con_l += __shfl_xor(con_l, 32); con_l *= 0.25f;

    __shared__ float part[4][33];
    if (lane < 16){
        part[wid][lane]      = nl_l;
        part[wid][16 + lane] = cs_l;
    }
    if (lane == 0) part[wid][32] = con_l;
    __syncthreads();
    if (tid < 33){
        float s = part[0][tid] + part[1][tid] + part[2][tid] + part[3][tid];
        atomicAdd(&red[tid * RSTRIDE], s);
    }
}

// ---------------- per-edge trace: sum_e dot(S[src], S[dst]) ----------------
__global__ __launch_bounds__(256) void edge_trace_kernel(const int* __restrict__ src,
        const int* __restrict__ dst, const float* __restrict__ as_,
        float* __restrict__ red, int E){
    int tid    = blockIdx.x * blockDim.x + threadIdx.x;
    int stride = gridDim.x * blockDim.x;
    float dot = 0.f;
    for (int i = tid; i < E; i += stride){
        const float4* pa = reinterpret_cast<const float4*>(as_ + (size_t)src[i] * 16);
        const float4* pb = reinterpret_cast<const float4*>(as_ + (size_t)dst[i] * 16);
        #pragma unroll
        for (int q = 0; q < 4; ++q){
            float4 va = pa[q]; float4 vb = pb[q];
            dot = fmaf(va.x, vb.x, dot); dot = fmaf(va.y, vb.y, dot);
            dot = fmaf(va.z, vb.z, dot); dot = fmaf(va.w, vb.w, dot);
        }
    }
    #pragma unroll
    for (int off = 1; off < 64; off <<= 1) dot += __shfl_xor(dot, off);
    __shared__ float part[4];
    int wid = threadIdx.x >> 6, lane = threadIdx.x & 63;
    if (lane == 0) part[wid] = dot;
    __syncthreads();
    if (threadIdx.x == 0)
        atomicAdd(&red[33 * RSTRIDE], part[0] + part[1] + part[2] + part[3]);
}

// ---------------- finalize ----------------
__global__ void finalize_kernel(const float* __restrict__ red, float* __restrict__ out,
                                int n, int E){
    float trace = red[33 * RSTRIDE];
    float nl2 = 0.f, cs2 = 0.f;
    #pragma unroll
    for (int k = 0; k < 16; ++k){
        nl2 = fmaf(red[k * RSTRIDE],        red[k * RSTRIDE],        nl2);
        cs2 = fmaf(red[(16 + k) * RSTRIDE], red[(16 + k) * RSTRIDE], cs2);
    }
    float twoE = 2.f * (float)E;
    float spectral = -(trace - nl2 / twoE) / twoE;
    float cluster  = sqrtf(cs2) / (float)n * 4.f - 1.f;
    float con      = red[32 * RSTRIDE] / (float)n;
    out[0] = spectral + cluster + con;
}

extern "C" void kernel_launch(void* const* d_in, const int* in_sizes, int n_in,
                              void* d_out, int out_size, void* d_ws, size_t ws_size,
                              hipStream_t stream){
    const int*   esrc = (const int*)d_in[0];
    const int*   edst = (const int*)d_in[1];
    const float* ew   = (const float*)d_in[2];
    const float* feat = (const float*)d_in[3];
    const float* faug = (const float*)d_in[4];
    const float* W1   = (const float*)d_in[5];
    const float* b1   = (const float*)d_in[6];
    const float* Wsm  = (const float*)d_in[7];
    const float* bsv  = (const float*)d_in[8];
    const float* Wtm  = (const float*)d_in[9];
    const float* btv  = (const float*)d_in[10];
    int E = in_sizes[0];
    int N = in_sizes[3] / Fdim;

    char* ws = (char*)d_ws;
    size_t off = 0;
    auto alloc = [&](size_t bytes) -> char* {
        char* p = ws + off;
        off = (off + bytes + 255) & ~(size_t)255;
        return p;
    };
    int nbuck = (N + 255) >> 8;
    unsigned char* XWp = (unsigned char*)alloc((size_t)N * 512);  // fp8 [N][512B]
    ushort*   Gs    = (ushort*)alloc((size_t)N * Hdim * 2);
    ushort*   Gt    = (ushort*)alloc((size_t)N * Hdim * 2);
    unsigned* GSp   = (unsigned*)alloc((size_t)N * Kc * 4);
    float*    ASG_S = (float*)alloc((size_t)N * Kc * 4);
    ushort*   WT    = (ushort*)alloc((size_t)256 * 256 * 2);
    ushort*   WsT   = (ushort*)alloc((size_t)16 * 256 * 2);
    ushort*   WtT   = (ushort*)alloc((size_t)16 * 256 * 2);
    int*      ROFF  = (int*)alloc((size_t)(N + 1) * 4);
    int*      CNT   = (int*)alloc((size_t)N * 4);
    int*      DEG   = (int*)alloc((size_t)N * 4);
    int*      BSUM  = (int*)alloc((size_t)256 * 4);
    int*      BCNT  = (int*)alloc((size_t)nbuck * 32 * 4);
    int*      BSRC  = (int*)alloc((size_t)nbuck * BCAP * 4);
    int*      BDST  = (int*)alloc((size_t)nbuck * BCAP * 4);
    float*    BW    = (float*)alloc((size_t)nbuck * BCAP * 4);
    uint2*    CSR8  = (uint2*)alloc((size_t)E * 8);
    float*    RED   = (float*)alloc((size_t)NRED * RSTRIDE * 4);

    hipMemsetAsync(CNT, 0, (size_t)N * 4, stream);
    hipMemsetAsync(DEG, 0, (size_t)N * 4, stream);
    hipMemsetAsync(BCNT, 0, (size_t)nbuck * 32 * 4, stream);
    hipMemsetAsync(RED, 0, (size_t)NRED * RSTRIDE * 4, stream);

    int eb = (E + 255) / 256;
    int nb = (N + 255) / 256;
    castw_kernel<<<dim3(16, 16), dim3(16, 16), 0, stream>>>(W1, WT);
    castwk_kernel<<<1, 256, 0, stream>>>(Wsm, Wtm, WsT, WtT);
    hist_bucket_kernel<<<eb, 256, 0, stream>>>(esrc, edst, ew, CNT, DEG, BCNT,
                                               BSRC, BDST, BW, E);
    scan1_kernel<<<nb, 256, 0, stream>>>(CNT, BSUM, N);
    scan2_kernel<<<1, 256, 0, stream>>>(BSUM, nb);
    scan3_kernel<<<nb, 256, 0, stream>>>(CNT, BSUM, ROFF, N);
    bucket_scatter_kernel<<<nbuck, 256, 0, stream>>>(BCNT, BSRC, BDST, BW, ROFF, CSR8);

    dim3 gg(2, (N + 127) / 128);
    gemm_xw_kernel<<<gg, 256, 0, stream>>>(feat, WT, XWp, N, 0);
    gemm_xw_kernel<<<gg, 256, 0, stream>>>(faug, WT, XWp, N, 256);

    spmm_h2_kernel<<<(N + 3) / 4, 256, 0, stream>>>(XWp, ROFF, CSR8, b1, Gs, Gt, N);

    int nw = (N + 15) / 16;
    gemm_k2_kernel<<<(nw + 3) / 4, 256, 0, stream>>>(Gs, Gt, WsT, WtT, GSp, N);

    spmm_k2_kernel<<<2048, 256, 0, stream>>>(GSp, ROFF, CSR8, bsv, btv,
                                             DEG, ASG_S, RED, N);

    edge_trace_kernel<<<256, 256, 0, stream>>>(esrc, edst, ASG_S, RED, E);
    finalize_kernel<<<1, 1, 0, stream>>>(RED, (float*)d_out, N, E);
}

// Round 9
// 288.849 us; speedup vs baseline: 3.1463x; 1.2091x over previous
//
#include <hip/hip_runtime.h>
#include <math.h>

constexpr int Fdim = 256;
constexpr int Hdim = 256;
constexpr int Kc   = 16;

constexpr int RSTRIDE = 32;
constexpr int NRED    = 34;   // 0..15 nl, 16..31 cluster_sizes, 32 con, 33 trace
constexpr int BCAP    = 5120; // bucket capacity (mean 4096, 16 sigma slack)

typedef __attribute__((ext_vector_type(8))) short s8v;   // 8 bf16 (4 VGPRs)
typedef __attribute__((ext_vector_type(4))) float f4v;   // 4 fp32 acc

__device__ __forceinline__ float selu1(float x){
    const float scale = 1.0507009873554805f;
    const float alpha = 1.6732632423543772f;
    return scale * (x > 0.f ? x : alpha * expm1f(x));
}

__device__ __forceinline__ ushort f2bf(float x){
    union { float f; unsigned u; } c; c.f = x;
    unsigned r = c.u + 0x7fffu + ((c.u >> 16) & 1u);   // RNE
    return (ushort)(r >> 16);
}

__device__ __forceinline__ float bflo(unsigned v){
    union { unsigned u; float f; } c; c.u = v << 16; return c.f;
}
__device__ __forceinline__ float bfhi(unsigned v){
    union { unsigned u; float f; } c; c.u = v & 0xffff0000u; return c.f;
}

// fp8 e4m3 encode via HW converter (RNE)
__device__ __forceinline__ unsigned char f2fp8(float x){
    int v = __builtin_amdgcn_cvt_pk_fp8_f32(x, x, 0, false);
    return (unsigned char)(v & 0xff);
}

// ---------------- CSR build phase A: LDS-staged binning + degree histogram ----------
__global__ __launch_bounds__(256) void bin_kernel(
        const int* __restrict__ src, const int* __restrict__ dst,
        const float* __restrict__ w,
        int* __restrict__ dcnt, int* __restrict__ bcnt,
        int* __restrict__ bsrc, uint2* __restrict__ bdw, int E, int nbuck){
    __shared__ int hist[256];
    __shared__ int base[256];
    __shared__ int cur[256];
    int t = threadIdx.x;
    int chunk = (E + gridDim.x - 1) / gridDim.x;
    int lo = blockIdx.x * chunk;
    int hi = min(lo + chunk, E);
    hist[t] = 0;
    __syncthreads();
    // pass 1: bucket histogram + dst-degree atomics
    for (int i = lo + t; i < hi; i += 256){
        int s = src[i];
        atomicAdd(&hist[s >> 8], 1);
        atomicAdd(&dcnt[dst[i]], 1);
    }
    __syncthreads();
    // reserve contiguous space per bucket
    if (t < nbuck && hist[t] > 0)
        base[t] = atomicAdd(&bcnt[t * 32], hist[t]);
    cur[t] = 0;
    __syncthreads();
    // pass 2: place edges densely per (block,bucket) group
    for (int i = lo + t; i < hi; i += 256){
        int s = src[i], d = dst[i];
        float wv = w[i];
        int b = s >> 8;
        int p = base[b] + atomicAdd(&cur[b], 1);
        if (p < BCAP){
            bsrc[(size_t)b * BCAP + p] = s;
            bdw[(size_t)b * BCAP + p]  = make_uint2((unsigned)d, __float_as_uint(wv));
        }
    }
}

// ---------------- per-bucket src counts (bucket spans exactly 256 src nodes) --------
__global__ __launch_bounds__(256) void scnt_kernel(
        const int* __restrict__ bcnt, const int* __restrict__ bsrc,
        int* __restrict__ scnt, int n){
    __shared__ int cnt[256];
    int b = blockIdx.x;
    cnt[threadIdx.x] = 0;
    __syncthreads();
    int c = min(bcnt[b * 32], BCAP);
    for (int t = threadIdx.x; t < c; t += 256)
        atomicAdd(&cnt[bsrc[(size_t)b * BCAP + t] & 255], 1);
    __syncthreads();
    int i = b * 256 + threadIdx.x;
    if (i < n) scnt[i] = cnt[threadIdx.x];
}

// hierarchical scan
__global__ __launch_bounds__(256) void scan1_kernel(const int* __restrict__ cnt,
                                                    int* __restrict__ bsum, int n){
    int i = blockIdx.x * 256 + threadIdx.x;
    int v = (i < n) ? cnt[i] : 0;
    #pragma unroll
    for (int off = 1; off < 64; off <<= 1) v += __shfl_xor(v, off);
    __shared__ int sdata[4];
    int wid = threadIdx.x >> 6, lane = threadIdx.x & 63;
    if (lane == 0) sdata[wid] = v;
    __syncthreads();
    if (threadIdx.x == 0) bsum[blockIdx.x] = sdata[0] + sdata[1] + sdata[2] + sdata[3];
}

__global__ __launch_bounds__(256) void scan2_kernel(int* __restrict__ bsum, int nb){
    __shared__ int s[256];
    int t = threadIdx.x;
    int v = (t < nb) ? bsum[t] : 0;
    s[t] = v;
    __syncthreads();
    for (int off = 1; off < 256; off <<= 1){
        int x = (t >= off) ? s[t - off] : 0;
        __syncthreads();
        s[t] += x;
        __syncthreads();
    }
    if (t < nb) bsum[t] = s[t] - v;   // exclusive
}

__global__ __launch_bounds__(256) void scan3_kernel(const int* __restrict__ cnt,
        const int* __restrict__ bsum, int* __restrict__ roff, int n){
    __shared__ int ls[256];
    int t = threadIdx.x;
    int i = blockIdx.x * 256 + t;
    int v = (i < n) ? cnt[i] : 0;
    ls[t] = v;
    __syncthreads();
    for (int off = 1; off < 256; off <<= 1){
        int x = (t >= off) ? ls[t - off] : 0;
        __syncthreads();
        ls[t] += x;
        __syncthreads();
    }
    int base = bsum[blockIdx.x];
    if (i < n)  roff[i] = base + ls[t] - v;
    if (i == n - 1) roff[n] = base + ls[t];
}

// ---------------- CSR build phase B: bucket-local scatter (LDS cursors) ----------
__global__ __launch_bounds__(256) void bucket_scatter_kernel(
        const int* __restrict__ bcnt, const int* __restrict__ bsrc,
        const uint2* __restrict__ bdw,
        const int* __restrict__ roff, uint2* __restrict__ csr){
    __shared__ int cur[256];
    int b = blockIdx.x;
    cur[threadIdx.x] = 0;
    __syncthreads();
    int cnt = min(bcnt[b * 32], BCAP);
    for (int t = threadIdx.x; t < cnt; t += 256){
        int s = bsrc[(size_t)b * BCAP + t];
        int p = roff[s] + atomicAdd(&cur[s & 255], 1);
        csr[p] = bdw[(size_t)b * BCAP + t];
    }
}

// ---------------- W1 transpose-cast: Wt[n][k] = bf16(W1[k][n]) ----------------
__global__ void castw_kernel(const float* __restrict__ W, ushort* __restrict__ Wt){
    __shared__ float t[16][17];
    int tx = threadIdx.x, ty = threadIdx.y;
    int k  = blockIdx.y * 16 + ty;
    int nn = blockIdx.x * 16 + tx;
    t[ty][tx] = W[k * 256 + nn];
    __syncthreads();
    int n2 = blockIdx.x * 16 + ty;
    int k2 = blockIdx.y * 16 + tx;
    Wt[n2 * 256 + k2] = f2bf(t[tx][ty]);
}

// ---------------- Ws/Wt transpose-cast ----------------
__global__ void castwk_kernel(const float* __restrict__ Ws, const float* __restrict__ Wt,
                              ushort* __restrict__ WsT, ushort* __restrict__ WtT){
    int h = threadIdx.x;   // 0..255
    #pragma unroll
    for (int c = 0; c < 16; ++c){
        WsT[c * 256 + h] = f2bf(Ws[h * 16 + c]);
        WtT[c * 256 + h] = f2bf(Wt[h * 16 + c]);
    }
}

// ---------------- MFMA bf16 GEMM: XWp_fp8[M][512B] (half sel) = A_f32 @ W ----------
__global__ __launch_bounds__(256, 2) void gemm_xw_kernel(
        const float* __restrict__ A, const ushort* __restrict__ Bt,
        unsigned char* __restrict__ C8, int M, int halfoff){
    __shared__ ushort blds[32768];
    int tid = threadIdx.x;
    int n0  = blockIdx.x * 128;
    int bm  = blockIdx.y * 128;

    #pragma unroll
    for (int j = 0; j < 16; ++j){
        int c  = j * 256 + tid;
        int nl = c >> 5, kc = c & 31;
        uint4 v = *reinterpret_cast<const uint4*>(Bt + (((size_t)(n0 + nl)) << 8) + (kc << 3));
        unsigned boff = (unsigned)(((nl << 9) + (kc << 4)) ^ ((nl & 7) << 4));
        *reinterpret_cast<uint4*>(reinterpret_cast<char*>(blds) + boff) = v;
    }
    __syncthreads();

    int w = tid >> 6, l = tid & 63;
    int lr = l & 15, lk = l >> 4;

    f4v acc[2][8];
    #pragma unroll
    for (int m = 0; m < 2; ++m)
        #pragma unroll
        for (int t = 0; t < 8; ++t)
            acc[m][t] = (f4v){0.f, 0.f, 0.f, 0.f};

    int r0 = bm + w * 32 + lr;
    int r1 = r0 + 16;
    int rc0 = min(r0, M - 1), rc1 = min(r1, M - 1);
    const float* a0 = A + (size_t)rc0 * 256 + lk * 8;
    const float* a1 = A + (size_t)rc1 * 256 + lk * 8;

    for (int ks = 0; ks < 8; ++ks){
        s8v af0, af1;
        {
            float4 f0 = *reinterpret_cast<const float4*>(a0 + ks * 32);
            float4 f1 = *reinterpret_cast<const float4*>(a0 + ks * 32 + 4);
            af0[0] = (short)f2bf(f0.x); af0[1] = (short)f2bf(f0.y);
            af0[2] = (short)f2bf(f0.z); af0[3] = (short)f2bf(f0.w);
            af0[4] = (short)f2bf(f1.x); af0[5] = (short)f2bf(f1.y);
            af0[6] = (short)f2bf(f1.z); af0[7] = (short)f2bf(f1.w);
        }
        {
            float4 f0 = *reinterpret_cast<const float4*>(a1 + ks * 32);
            float4 f1 = *reinterpret_cast<const float4*>(a1 + ks * 32 + 4);
            af1[0] = (short)f2bf(f0.x); af1[1] = (short)f2bf(f0.y);
            af1[2] = (short)f2bf(f0.z); af1[3] = (short)f2bf(f0.w);
            af1[4] = (short)f2bf(f1.x); af1[5] = (short)f2bf(f1.y);
            af1[6] = (short)f2bf(f1.z); af1[7] = (short)f2bf(f1.w);
        }
        #pragma unroll
        for (int t = 0; t < 8; ++t){
            int nl = t * 16 + lr;
            unsigned boff = (unsigned)(((nl << 9) + ((ks * 4 + lk) << 4)) ^ ((nl & 7) << 4));
            s8v bf = *reinterpret_cast<const s8v*>(reinterpret_cast<const char*>(blds) + boff);
            acc[0][t] = __builtin_amdgcn_mfma_f32_16x16x32_bf16(af0, bf, acc[0][t], 0, 0, 0);
            acc[1][t] = __builtin_amdgcn_mfma_f32_16x16x32_bf16(af1, bf, acc[1][t], 0, 0, 0);
        }
    }

    // fp8 store: byte addr = row*512 + halfoff + col
    #pragma unroll
    for (int m = 0; m < 2; ++m){
        #pragma unroll
        for (int t = 0; t < 8; ++t){
            int col = n0 + t * 16 + lr;
            #pragma unroll
            for (int j = 0; j < 4; ++j){
                int row = bm + w * 32 + m * 16 + lk * 4 + j;
                if (row < M) C8[(size_t)row * 512 + halfoff + col] = f2fp8(acc[m][t][j]);
            }
        }
    }
}

// ---------------- fused SPMM over H=256 (student+teacher), fp8 table, + bias + selu ----
__global__ __launch_bounds__(256) void spmm_h2_kernel(
        const unsigned char* __restrict__ XWp,
        const int* __restrict__ roff, const uint2* __restrict__ csr,
        const float* __restrict__ b1,
        ushort* __restrict__ Gs, ushort* __restrict__ Gt, int n){
    int wid = threadIdx.x >> 6, lane = threadIdx.x & 63;
    int r = blockIdx.x * 4 + wid;
    if (r >= n) return;
    int half = lane >> 5;          // 0 = student, 1 = teacher
    int hl   = lane & 31;          // col group: cols hl*8 .. hl*8+7
    const unsigned char* base = XWp + lane * 8;
    int e0 = roff[r], e1 = roff[r + 1];
    float acc[8] = {};

    #define ACCUM8(V, W) do{                                                      \
        auto fa_ = __builtin_amdgcn_cvt_pk_f32_fp8((V).x, false);                 \
        acc[0] = fmaf((W), fa_[0], acc[0]); acc[1] = fmaf((W), fa_[1], acc[1]);   \
        auto fb_ = __builtin_amdgcn_cvt_pk_f32_fp8((V).x, true);                  \
        acc[2] = fmaf((W), fb_[0], acc[2]); acc[3] = fmaf((W), fb_[1], acc[3]);   \
        auto fc_ = __builtin_amdgcn_cvt_pk_f32_fp8((V).y, false);                 \
        acc[4] = fmaf((W), fc_[0], acc[4]); acc[5] = fmaf((W), fc_[1], acc[5]);   \
        auto fd_ = __builtin_amdgcn_cvt_pk_f32_fp8((V).y, true);                  \
        acc[6] = fmaf((W), fd_[0], acc[6]); acc[7] = fmaf((W), fd_[1], acc[7]);   \
    }while(0)

    int e = e0;
    for (; e + 3 < e1; e += 4){
        uint2 c0 = csr[e],     c1 = csr[e + 1];
        uint2 c2 = csr[e + 2], c3 = csr[e + 3];
        float w0 = __uint_as_float(c0.y), w1 = __uint_as_float(c1.y);
        float w2 = __uint_as_float(c2.y), w3 = __uint_as_float(c3.y);
        uint2 v0 = *reinterpret_cast<const uint2*>(base + ((size_t)c0.x << 9));
        uint2 v1 = *reinterpret_cast<const uint2*>(base + ((size_t)c1.x << 9));
        uint2 v2 = *reinterpret_cast<const uint2*>(base + ((size_t)c2.x << 9));
        uint2 v3 = *reinterpret_cast<const uint2*>(base + ((size_t)c3.x << 9));
        ACCUM8(v0, w0); ACCUM8(v1, w1); ACCUM8(v2, w2); ACCUM8(v3, w3);
    }
    for (; e < e1; ++e){
        uint2 c = csr[e];
        float w = __uint_as_float(c.y);
        uint2 v = *reinterpret_cast<const uint2*>(base + ((size_t)c.x << 9));
        ACCUM8(v, w);
    }
    #undef ACCUM8

    const float* bp = b1 + hl * 8;
    float4 bb0 = *reinterpret_cast<const float4*>(bp);
    float4 bb1 = *reinterpret_cast<const float4*>(bp + 4);
    float bv[8] = {bb0.x, bb0.y, bb0.z, bb0.w, bb1.x, bb1.y, bb1.z, bb1.w};
    ushort o[8];
    #pragma unroll
    for (int q = 0; q < 8; ++q) o[q] = f2bf(selu1(acc[q] + bv[q]));
    uint4 ov = *reinterpret_cast<const uint4*>(o);
    ushort* gout = (half ? Gt : Gs) + (size_t)r * Hdim + hl * 8;
    *reinterpret_cast<uint4*>(gout) = ov;
}

// ---------------- fused MFMA: GS = pack(Gs@Ws, Gt@Wt) bf16   [N,256]x[256,16] ----------
__global__ __launch_bounds__(256) void gemm_k2_kernel(
        const ushort* __restrict__ Gs, const ushort* __restrict__ Gt,
        const ushort* __restrict__ WsT, const ushort* __restrict__ WtT,
        unsigned* __restrict__ GSp, int n){
    int wv = blockIdx.x * 4 + (threadIdx.x >> 6);
    int l  = threadIdx.x & 63;
    int lr = l & 15, lk = l >> 4;
    int nw = (n + 15) >> 4;
    if (wv >= nw) return;
    int r0 = wv * 16;

    s8v bs_[8], bt_[8];
    #pragma unroll
    for (int ks = 0; ks < 8; ++ks){
        bs_[ks] = *reinterpret_cast<const s8v*>(WsT + lr * 256 + ks * 32 + lk * 8);
        bt_[ks] = *reinterpret_cast<const s8v*>(WtT + lr * 256 + ks * 32 + lk * 8);
    }

    f4v accs = (f4v){0.f,0.f,0.f,0.f}, acct = (f4v){0.f,0.f,0.f,0.f};
    int row = min(r0 + lr, n - 1);
    const ushort* gsrow = Gs + (size_t)row * 256 + lk * 8;
    const ushort* gtrow = Gt + (size_t)row * 256 + lk * 8;
    #pragma unroll
    for (int ks = 0; ks < 8; ++ks){
        s8v a_s = *reinterpret_cast<const s8v*>(gsrow + ks * 32);
        s8v a_t = *reinterpret_cast<const s8v*>(gtrow + ks * 32);
        accs = __builtin_amdgcn_mfma_f32_16x16x32_bf16(a_s, bs_[ks], accs, 0, 0, 0);
        acct = __builtin_amdgcn_mfma_f32_16x16x32_bf16(a_t, bt_[ks], acct, 0, 0, 0);
    }
    #pragma unroll
    for (int j = 0; j < 4; ++j){
        int rr = r0 + lk * 4 + j;
        if (rr < n){
            unsigned pv = (unsigned)f2bf(accs[j]) | ((unsigned)f2bf(acct[j]) << 16);
            GSp[(size_t)rr * 16 + lr] = pv;
        }
    }
}

// ---------------- fused: SPMM-K + softmax (both branches) + node stats ----------------
__global__ __launch_bounds__(256) void spmm_k2_kernel(
        const unsigned* __restrict__ GSp,
        const int* __restrict__ roff, const uint2* __restrict__ csr,
        const float* __restrict__ bsv, const float* __restrict__ btv,
        const int* __restrict__ deg,
        float* __restrict__ asg, float* __restrict__ red, int n){
    int tid  = threadIdx.x;
    int wid  = tid >> 6, lane = tid & 63;
    int slot = lane >> 4, j = lane & 15;
    float bs_ = bsv[j], bt_ = btv[j];
    float nl_l = 0.f, cs_l = 0.f, con_l = 0.f;

    int rstride = gridDim.x * 4;
    for (int r = blockIdx.x * 4 + wid; r < n; r += rstride){
        int e0 = roff[r], e1 = roff[r + 1];
        float as_ = 0.f, at_ = 0.f;
        for (int e = e0 + slot; e < e1; e += 4){
            uint2 c = csr[e];
            float w = __uint_as_float(c.y);
            unsigned v = GSp[(size_t)c.x * 16 + j];
            as_ = fmaf(w, bflo(v), as_);
            at_ = fmaf(w, bfhi(v), at_);
        }
        as_ += __shfl_xor(as_, 16); as_ += __shfl_xor(as_, 32);
        at_ += __shfl_xor(at_, 16); at_ += __shfl_xor(at_, 32);
        float xs = selu1(as_ + bs_);
        float xt = selu1(at_ + bt_);
        float ms = xs, mt = xt;
        #pragma unroll
        for (int off = 8; off >= 1; off >>= 1){
            ms = fmaxf(ms, __shfl_xor(ms, off));
            mt = fmaxf(mt, __shfl_xor(mt, off));
        }
        float es = expf(xs - ms), et = expf(xt - mt);
        float ss = es, st = et;
        #pragma unroll
        for (int off = 8; off >= 1; off >>= 1){
            ss += __shfl_xor(ss, off);
            st += __shfl_xor(st, off);
        }
        float a = es / ss, b = et / st;
        if (slot == 0) asg[(size_t)r * 16 + j] = a;
        float dgr = (float)deg[r];
        nl_l += a * dgr;
        cs_l += a;
        float dot = a * b, na = a * a, nb = b * b;
        #pragma unroll
        for (int off = 8; off >= 1; off >>= 1){
            dot += __shfl_xor(dot, off);
            na  += __shfl_xor(na, off);
            nb  += __shfl_xor(nb, off);
        }
        if (j == 0){
            na = fmaxf(sqrtf(na), 1e-12f);
            nb = fmaxf(sqrtf(nb), 1e-12f);
            con_l += 2.f - 2.f * dot / (na * nb);
        }
    }

    // slots hold exact duplicates -> combine then scale by 1/4
    nl_l  += __shfl_xor(nl_l, 16);  nl_l  += __shfl_xor(nl_l, 32);  nl_l  *= 0.25f;
    cs_l  += __shfl_xor(cs_l, 16);  cs_l  += __shfl_xor(cs_l, 32);  cs_l  *= 0.25f;
    con_l += __shfl_xor(con_l, 16); con_l += __shfl_xor(con_l, 32); con_l *= 0.25f;

    __shared__ float part[4][33];
    if (lane < 16){
        part[wid][lane]      = nl_l;
        part[wid][16 + lane] = cs_l;
    }
    if (lane == 0) part[wid][32] = con_l;
    __syncthreads();
    if (tid < 33){
        float s = part[0][tid] + part[1][tid] + part[2][tid] + part[3][tid];
        atomicAdd(&red[tid * RSTRIDE], s);
    }
}

// ---------------- per-edge trace: sum_e dot(S[src], S[dst]) ----------------
__global__ __launch_bounds__(256) void edge_trace_kernel(const int* __restrict__ src,
        const int* __restrict__ dst, const float* __restrict__ as_,
        float* __restrict__ red, int E){
    int tid    = blockIdx.x * blockDim.x + threadIdx.x;
    int stride = gridDim.x * blockDim.x;
    float dot = 0.f;
    for (int i = tid; i < E; i += stride){
        const float4* pa = reinterpret_cast<const float4*>(as_ + (size_t)src[i] * 16);
        const float4* pb = reinterpret_cast<const float4*>(as_ + (size_t)dst[i] * 16);
        #pragma unroll
        for (int q = 0; q < 4; ++q){
            float4 va = pa[q]; float4 vb = pb[q];
            dot = fmaf(va.x, vb.x, dot); dot = fmaf(va.y, vb.y, dot);
            dot = fmaf(va.z, vb.z, dot); dot = fmaf(va.w, vb.w, dot);
        }
    }
    #pragma unroll
    for (int off = 1; off < 64; off <<= 1) dot += __shfl_xor(dot, off);
    __shared__ float part[4];
    int wid = threadIdx.x >> 6, lane = threadIdx.x & 63;
    if (lane == 0) part[wid] = dot;
    __syncthreads();
    if (threadIdx.x == 0)
        atomicAdd(&red[33 * RSTRIDE], part[0] + part[1] + part[2] + part[3]);
}

// ---------------- finalize ----------------
__global__ void finalize_kernel(const float* __restrict__ red, float* __restrict__ out,
                                int n, int E){
    float trace = red[33 * RSTRIDE];
    float nl2 = 0.f, cs2 = 0.f;
    #pragma unroll
    for (int k = 0; k < 16; ++k){
        nl2 = fmaf(red[k * RSTRIDE],        red[k * RSTRIDE],        nl2);
        cs2 = fmaf(red[(16 + k) * RSTRIDE], red[(16 + k) * RSTRIDE], cs2);
    }
    float twoE = 2.f * (float)E;
    float spectral = -(trace - nl2 / twoE) / twoE;
    float cluster  = sqrtf(cs2) / (float)n * 4.f - 1.f;
    float con      = red[32 * RSTRIDE] / (float)n;
    out[0] = spectral + cluster + con;
}

extern "C" void kernel_launch(void* const* d_in, const int* in_sizes, int n_in,
                              void* d_out, int out_size, void* d_ws, size_t ws_size,
                              hipStream_t stream){
    const int*   esrc = (const int*)d_in[0];
    const int*   edst = (const int*)d_in[1];
    const float* ew   = (const float*)d_in[2];
    const float* feat = (const float*)d_in[3];
    const float* faug = (const float*)d_in[4];
    const float* W1   = (const float*)d_in[5];
    const float* b1   = (const float*)d_in[6];
    const float* Wsm  = (const float*)d_in[7];
    const float* bsv  = (const float*)d_in[8];
    const float* Wtm  = (const float*)d_in[9];
    const float* btv  = (const float*)d_in[10];
    int E = in_sizes[0];
    int N = in_sizes[3] / Fdim;

    char* ws = (char*)d_ws;
    size_t off = 0;
    auto alloc = [&](size_t bytes) -> char* {
        char* p = ws + off;
        off = (off + bytes + 255) & ~(size_t)255;
        return p;
    };
    int nbuck = (N + 255) >> 8;
    unsigned char* XWp = (unsigned char*)alloc((size_t)N * 512);  // fp8 [N][512B]
    ushort*   Gs    = (ushort*)alloc((size_t)N * Hdim * 2);
    ushort*   Gt    = (ushort*)alloc((size_t)N * Hdim * 2);
    unsigned* GSp   = (unsigned*)alloc((size_t)N * Kc * 4);
    float*    ASG_S = (float*)alloc((size_t)N * Kc * 4);
    ushort*   WT    = (ushort*)alloc((size_t)256 * 256 * 2);
    ushort*   WsT   = (ushort*)alloc((size_t)16 * 256 * 2);
    ushort*   WtT   = (ushort*)alloc((size_t)16 * 256 * 2);
    int*      ROFF  = (int*)alloc((size_t)(N + 1) * 4);
    int*      CNT   = (int*)alloc((size_t)N * 4);
    int*      DEG   = (int*)alloc((size_t)N * 4);
    int*      BSUM  = (int*)alloc((size_t)256 * 4);
    int*      BCNT  = (int*)alloc((size_t)nbuck * 32 * 4);
    int*      BSRC  = (int*)alloc((size_t)nbuck * BCAP * 4);
    uint2*    BDW   = (uint2*)alloc((size_t)nbuck * BCAP * 8);
    uint2*    CSR8  = (uint2*)alloc((size_t)E * 8);
    float*    RED   = (float*)alloc((size_t)NRED * RSTRIDE * 4);

    hipMemsetAsync(DEG, 0, (size_t)N * 4, stream);
    hipMemsetAsync(BCNT, 0, (size_t)nbuck * 32 * 4, stream);
    hipMemsetAsync(RED, 0, (size_t)NRED * RSTRIDE * 4, stream);

    int nb = (N + 255) / 256;
    castw_kernel<<<dim3(16, 16), dim3(16, 16), 0, stream>>>(W1, WT);
    castwk_kernel<<<1, 256, 0, stream>>>(Wsm, Wtm, WsT, WtT);
    bin_kernel<<<256, 256, 0, stream>>>(esrc, edst, ew, DEG, BCNT, BSRC, BDW, E, nbuck);
    scnt_kernel<<<nbuck, 256, 0, stream>>>(BCNT, BSRC, CNT, N);
    scan1_kernel<<<nb, 256, 0, stream>>>(CNT, BSUM, N);
    scan2_kernel<<<1, 256, 0, stream>>>(BSUM, nb);
    scan3_kernel<<<nb, 256, 0, stream>>>(CNT, BSUM, ROFF, N);
    bucket_scatter_kernel<<<nbuck, 256, 0, stream>>>(BCNT, BSRC, BDW, ROFF, CSR8);

    dim3 gg(2, (N + 127) / 128);
    gemm_xw_kernel<<<gg, 256, 0, stream>>>(feat, WT, XWp, N, 0);
    gemm_xw_kernel<<<gg, 256, 0, stream>>>(faug, WT, XWp, N, 256);

    spmm_h2_kernel<<<(N + 3) / 4, 256, 0, stream>>>(XWp, ROFF, CSR8, b1, Gs, Gt, N);

    int nw = (N + 15) / 16;
    gemm_k2_kernel<<<(nw + 3) / 4, 256, 0, stream>>>(Gs, Gt, WsT, WtT, GSp, N);

    spmm_k2_kernel<<<2048, 256, 0, stream>>>(GSp, ROFF, CSR8, bsv, btv,
                                             DEG, ASG_S, RED, N);

    edge_trace_kernel<<<256, 256, 0, stream>>>(esrc, edst, ASG_S, RED, E);
    finalize_kernel<<<1, 1, 0, stream>>>(RED, (float*)d_out, N, E);
}

// Round 10
// 248.203 us; speedup vs baseline: 3.6615x; 1.1638x over previous
//
#include <hip/hip_runtime.h>
#include <math.h>

constexpr int Fdim = 256;
constexpr int Hdim = 256;
constexpr int Kc   = 16;

constexpr int RSTRIDE = 32;
constexpr int NRED    = 34;   // 0..15 nl, 16..31 cluster_sizes, 32 con, 33 trace
constexpr int BCAP    = 5120; // bucket capacity (mean 4096, 16 sigma slack)

typedef __attribute__((ext_vector_type(8))) short s8v;   // 8 bf16 (4 VGPRs)
typedef __attribute__((ext_vector_type(4))) float f4v;   // 4 fp32 acc

__device__ __forceinline__ float selu1(float x){
    const float scale = 1.0507009873554805f;
    const float alpha = 1.6732632423543772f;
    return scale * (x > 0.f ? x : alpha * expm1f(x));
}

__device__ __forceinline__ ushort f2bf(float x){
    union { float f; unsigned u; } c; c.f = x;
    unsigned r = c.u + 0x7fffu + ((c.u >> 16) & 1u);   // RNE
    return (ushort)(r >> 16);
}

__device__ __forceinline__ float bflo(unsigned v){
    union { unsigned u; float f; } c; c.u = v << 16; return c.f;
}
__device__ __forceinline__ float bfhi(unsigned v){
    union { unsigned u; float f; } c; c.u = v & 0xffff0000u; return c.f;
}

// fp8 e4m3 encode via HW converter (RNE)
__device__ __forceinline__ unsigned char f2fp8(float x){
    int v = __builtin_amdgcn_cvt_pk_fp8_f32(x, x, 0, false);
    return (unsigned char)(v & 0xff);
}

// ---------------- CSR build phase A: LDS-staged binning (no degree atomics) --------
__global__ __launch_bounds__(256) void bin_kernel(
        const int* __restrict__ src, const int* __restrict__ dst,
        const float* __restrict__ w,
        int* __restrict__ bcnt,
        int* __restrict__ bsrc, uint2* __restrict__ bdw, int E, int nbuck){
    __shared__ int hist[256];
    __shared__ int base[256];
    __shared__ int cur[256];
    int t = threadIdx.x;
    int chunk = (E + gridDim.x - 1) / gridDim.x;
    int lo = blockIdx.x * chunk;
    int hi = min(lo + chunk, E);
    hist[t] = 0;
    __syncthreads();
    // pass 1: bucket histogram (reads src only)
    for (int i = lo + t; i < hi; i += 256)
        atomicAdd(&hist[src[i] >> 8], 1);
    __syncthreads();
    // reserve contiguous space per bucket
    if (t < nbuck && hist[t] > 0)
        base[t] = atomicAdd(&bcnt[t * 32], hist[t]);
    cur[t] = 0;
    __syncthreads();
    // pass 2: place edges densely per (block,bucket) group
    for (int i = lo + t; i < hi; i += 256){
        int s = src[i], d = dst[i];
        float wv = w[i];
        int b = s >> 8;
        int p = base[b] + atomicAdd(&cur[b], 1);
        if (p < BCAP){
            bsrc[(size_t)b * BCAP + p] = s;
            bdw[(size_t)b * BCAP + p]  = make_uint2((unsigned)d, __float_as_uint(wv));
        }
    }
}

// ---------------- bucket-base scan (single block) + roff[n] ----------------
__global__ __launch_bounds__(256) void bbase_kernel(const int* __restrict__ bcnt,
        int* __restrict__ bbase, int* __restrict__ roff, int nbuck, int n){
    __shared__ int s[256];
    int t = threadIdx.x;
    int v = (t < nbuck) ? min(bcnt[t * 32], BCAP) : 0;
    s[t] = v;
    __syncthreads();
    for (int off = 1; off < 256; off <<= 1){
        int x = (t >= off) ? s[t - off] : 0;
        __syncthreads();
        s[t] += x;
        __syncthreads();
    }
    if (t < nbuck) bbase[t] = s[t] - v;   // exclusive
    if (t == 255) roff[n] = s[255];       // total = E
}

// ---------------- per-bucket: src hist + scan -> roff slice, then scatter ----------
__global__ __launch_bounds__(256) void csr_build_kernel(
        const int* __restrict__ bcnt, const int* __restrict__ bbase,
        const int* __restrict__ bsrc, const uint2* __restrict__ bdw,
        int* __restrict__ roff, uint2* __restrict__ csr, int n){
    __shared__ int hist[256];
    __shared__ int loc[256];
    __shared__ int cur[256];
    int b = blockIdx.x, t = threadIdx.x;
    int cnt  = min(bcnt[b * 32], BCAP);
    int base = bbase[b];
    hist[t] = 0;
    __syncthreads();
    for (int i = t; i < cnt; i += 256)
        atomicAdd(&hist[bsrc[(size_t)b * BCAP + i] & 255], 1);
    __syncthreads();
    int v = hist[t];
    loc[t] = v;
    __syncthreads();
    for (int off = 1; off < 256; off <<= 1){
        int x = (t >= off) ? loc[t - off] : 0;
        __syncthreads();
        loc[t] += x;
        __syncthreads();
    }
    int gi = b * 256 + t;
    if (gi < n) roff[gi] = base + loc[t] - v;
    cur[t] = 0;
    __syncthreads();
    for (int i = t; i < cnt; i += 256){
        int s   = bsrc[(size_t)b * BCAP + i];
        int idx = s & 255;
        int p = base + (loc[idx] - hist[idx]) + atomicAdd(&cur[idx], 1);
        csr[p] = bdw[(size_t)b * BCAP + i];
    }
}

// ---------------- W1 transpose-cast: Wt[n][k] = bf16(W1[k][n]) ----------------
__global__ void castw_kernel(const float* __restrict__ W, ushort* __restrict__ Wt){
    __shared__ float t[16][17];
    int tx = threadIdx.x, ty = threadIdx.y;
    int k  = blockIdx.y * 16 + ty;
    int nn = blockIdx.x * 16 + tx;
    t[ty][tx] = W[k * 256 + nn];
    __syncthreads();
    int n2 = blockIdx.x * 16 + ty;
    int k2 = blockIdx.y * 16 + tx;
    Wt[n2 * 256 + k2] = f2bf(t[tx][ty]);
}

// ---------------- Ws/Wt transpose-cast ----------------
__global__ void castwk_kernel(const float* __restrict__ Ws, const float* __restrict__ Wt,
                              ushort* __restrict__ WsT, ushort* __restrict__ WtT){
    int h = threadIdx.x;   // 0..255
    #pragma unroll
    for (int c = 0; c < 16; ++c){
        WsT[c * 256 + h] = f2bf(Ws[h * 16 + c]);
        WtT[c * 256 + h] = f2bf(Wt[h * 16 + c]);
    }
}

// ---------------- MFMA bf16 GEMM (both branches via blockIdx.z) ----------
__global__ __launch_bounds__(256, 2) void gemm_xw_kernel(
        const float* __restrict__ A0, const float* __restrict__ A1,
        const ushort* __restrict__ Bt,
        unsigned char* __restrict__ C8, int M){
    __shared__ ushort blds[32768];
    int tid = threadIdx.x;
    int n0  = blockIdx.x * 128;
    int bm  = blockIdx.y * 128;
    const float* A = blockIdx.z ? A1 : A0;
    int halfoff = blockIdx.z * 256;

    #pragma unroll
    for (int j = 0; j < 16; ++j){
        int c  = j * 256 + tid;
        int nl = c >> 5, kc = c & 31;
        uint4 v = *reinterpret_cast<const uint4*>(Bt + (((size_t)(n0 + nl)) << 8) + (kc << 3));
        unsigned boff = (unsigned)(((nl << 9) + (kc << 4)) ^ ((nl & 7) << 4));
        *reinterpret_cast<uint4*>(reinterpret_cast<char*>(blds) + boff) = v;
    }
    __syncthreads();

    int w = tid >> 6, l = tid & 63;
    int lr = l & 15, lk = l >> 4;

    f4v acc[2][8];
    #pragma unroll
    for (int m = 0; m < 2; ++m)
        #pragma unroll
        for (int t = 0; t < 8; ++t)
            acc[m][t] = (f4v){0.f, 0.f, 0.f, 0.f};

    int r0 = bm + w * 32 + lr;
    int r1 = r0 + 16;
    int rc0 = min(r0, M - 1), rc1 = min(r1, M - 1);
    const float* a0 = A + (size_t)rc0 * 256 + lk * 8;
    const float* a1 = A + (size_t)rc1 * 256 + lk * 8;

    for (int ks = 0; ks < 8; ++ks){
        s8v af0, af1;
        {
            float4 f0 = *reinterpret_cast<const float4*>(a0 + ks * 32);
            float4 f1 = *reinterpret_cast<const float4*>(a0 + ks * 32 + 4);
            af0[0] = (short)f2bf(f0.x); af0[1] = (short)f2bf(f0.y);
            af0[2] = (short)f2bf(f0.z); af0[3] = (short)f2bf(f0.w);
            af0[4] = (short)f2bf(f1.x); af0[5] = (short)f2bf(f1.y);
            af0[6] = (short)f2bf(f1.z); af0[7] = (short)f2bf(f1.w);
        }
        {
            float4 f0 = *reinterpret_cast<const float4*>(a1 + ks * 32);
            float4 f1 = *reinterpret_cast<const float4*>(a1 + ks * 32 + 4);
            af1[0] = (short)f2bf(f0.x); af1[1] = (short)f2bf(f0.y);
            af1[2] = (short)f2bf(f0.z); af1[3] = (short)f2bf(f0.w);
            af1[4] = (short)f2bf(f1.x); af1[5] = (short)f2bf(f1.y);
            af1[6] = (short)f2bf(f1.z); af1[7] = (short)f2bf(f1.w);
        }
        #pragma unroll
        for (int t = 0; t < 8; ++t){
            int nl = t * 16 + lr;
            unsigned boff = (unsigned)(((nl << 9) + ((ks * 4 + lk) << 4)) ^ ((nl & 7) << 4));
            s8v bf = *reinterpret_cast<const s8v*>(reinterpret_cast<const char*>(blds) + boff);
            acc[0][t] = __builtin_amdgcn_mfma_f32_16x16x32_bf16(af0, bf, acc[0][t], 0, 0, 0);
            acc[1][t] = __builtin_amdgcn_mfma_f32_16x16x32_bf16(af1, bf, acc[1][t], 0, 0, 0);
        }
    }

    // fp8 store: byte addr = row*512 + halfoff + col
    #pragma unroll
    for (int m = 0; m < 2; ++m){
        #pragma unroll
        for (int t = 0; t < 8; ++t){
            int col = n0 + t * 16 + lr;
            #pragma unroll
            for (int j = 0; j < 4; ++j){
                int row = bm + w * 32 + m * 16 + lk * 4 + j;
                if (row < M) C8[(size_t)row * 512 + halfoff + col] = f2fp8(acc[m][t][j]);
            }
        }
    }
}

// ---------------- fused SPMM over H=256 (student+teacher), fp8 table, + bias + selu ----
__global__ __launch_bounds__(256) void spmm_h2_kernel(
        const unsigned char* __restrict__ XWp,
        const int* __restrict__ roff, const uint2* __restrict__ csr,
        const float* __restrict__ b1,
        ushort* __restrict__ Gs, ushort* __restrict__ Gt, int n){
    int wid = threadIdx.x >> 6, lane = threadIdx.x & 63;
    int r = blockIdx.x * 4 + wid;
    if (r >= n) return;
    int half = lane >> 5;          // 0 = student, 1 = teacher
    int hl   = lane & 31;          // col group: cols hl*8 .. hl*8+7
    const unsigned char* base = XWp + lane * 8;
    int e0 = roff[r], e1 = roff[r + 1];
    float acc[8] = {};

    #define ACCUM8(V, W) do{                                                      \
        auto fa_ = __builtin_amdgcn_cvt_pk_f32_fp8((V).x, false);                 \
        acc[0] = fmaf((W), fa_[0], acc[0]); acc[1] = fmaf((W), fa_[1], acc[1]);   \
        auto fb_ = __builtin_amdgcn_cvt_pk_f32_fp8((V).x, true);                  \
        acc[2] = fmaf((W), fb_[0], acc[2]); acc[3] = fmaf((W), fb_[1], acc[3]);   \
        auto fc_ = __builtin_amdgcn_cvt_pk_f32_fp8((V).y, false);                 \
        acc[4] = fmaf((W), fc_[0], acc[4]); acc[5] = fmaf((W), fc_[1], acc[5]);   \
        auto fd_ = __builtin_amdgcn_cvt_pk_f32_fp8((V).y, true);                  \
        acc[6] = fmaf((W), fd_[0], acc[6]); acc[7] = fmaf((W), fd_[1], acc[7]);   \
    }while(0)

    int e = e0;
    for (; e + 7 < e1; e += 8){
        uint2 c0 = csr[e],     c1 = csr[e + 1];
        uint2 c2 = csr[e + 2], c3 = csr[e + 3];
        uint2 c4 = csr[e + 4], c5 = csr[e + 5];
        uint2 c6 = csr[e + 6], c7 = csr[e + 7];
        uint2 v0 = *reinterpret_cast<const uint2*>(base + ((size_t)c0.x << 9));
        uint2 v1 = *reinterpret_cast<const uint2*>(base + ((size_t)c1.x << 9));
        uint2 v2 = *reinterpret_cast<const uint2*>(base + ((size_t)c2.x << 9));
        uint2 v3 = *reinterpret_cast<const uint2*>(base + ((size_t)c3.x << 9));
        uint2 v4 = *reinterpret_cast<const uint2*>(base + ((size_t)c4.x << 9));
        uint2 v5 = *reinterpret_cast<const uint2*>(base + ((size_t)c5.x << 9));
        uint2 v6 = *reinterpret_cast<const uint2*>(base + ((size_t)c6.x << 9));
        uint2 v7 = *reinterpret_cast<const uint2*>(base + ((size_t)c7.x << 9));
        ACCUM8(v0, __uint_as_float(c0.y)); ACCUM8(v1, __uint_as_float(c1.y));
        ACCUM8(v2, __uint_as_float(c2.y)); ACCUM8(v3, __uint_as_float(c3.y));
        ACCUM8(v4, __uint_as_float(c4.y)); ACCUM8(v5, __uint_as_float(c5.y));
        ACCUM8(v6, __uint_as_float(c6.y)); ACCUM8(v7, __uint_as_float(c7.y));
    }
    for (; e + 3 < e1; e += 4){
        uint2 c0 = csr[e],     c1 = csr[e + 1];
        uint2 c2 = csr[e + 2], c3 = csr[e + 3];
        uint2 v0 = *reinterpret_cast<const uint2*>(base + ((size_t)c0.x << 9));
        uint2 v1 = *reinterpret_cast<const uint2*>(base + ((size_t)c1.x << 9));
        uint2 v2 = *reinterpret_cast<const uint2*>(base + ((size_t)c2.x << 9));
        uint2 v3 = *reinterpret_cast<const uint2*>(base + ((size_t)c3.x << 9));
        ACCUM8(v0, __uint_as_float(c0.y)); ACCUM8(v1, __uint_as_float(c1.y));
        ACCUM8(v2, __uint_as_float(c2.y)); ACCUM8(v3, __uint_as_float(c3.y));
    }
    for (; e < e1; ++e){
        uint2 c = csr[e];
        uint2 v = *reinterpret_cast<const uint2*>(base + ((size_t)c.x << 9));
        ACCUM8(v, __uint_as_float(c.y));
    }
    #undef ACCUM8

    const float* bp = b1 + hl * 8;
    float4 bb0 = *reinterpret_cast<const float4*>(bp);
    float4 bb1 = *reinterpret_cast<const float4*>(bp + 4);
    float bv[8] = {bb0.x, bb0.y, bb0.z, bb0.w, bb1.x, bb1.y, bb1.z, bb1.w};
    ushort o[8];
    #pragma unroll
    for (int q = 0; q < 8; ++q) o[q] = f2bf(selu1(acc[q] + bv[q]));
    uint4 ov = *reinterpret_cast<const uint4*>(o);
    ushort* gout = (half ? Gt : Gs) + (size_t)r * Hdim + hl * 8;
    *reinterpret_cast<uint4*>(gout) = ov;
}

// ---------------- fused MFMA: GS = pack(Gs@Ws, Gt@Wt) bf16   [N,256]x[256,16] ----------
__global__ __launch_bounds__(256) void gemm_k2_kernel(
        const ushort* __restrict__ Gs, const ushort* __restrict__ Gt,
        const ushort* __restrict__ WsT, const ushort* __restrict__ WtT,
        unsigned* __restrict__ GSp, int n){
    int wv = blockIdx.x * 4 + (threadIdx.x >> 6);
    int l  = threadIdx.x & 63;
    int lr = l & 15, lk = l >> 4;
    int nw = (n + 15) >> 4;
    if (wv >= nw) return;
    int r0 = wv * 16;

    s8v bs_[8], bt_[8];
    #pragma unroll
    for (int ks = 0; ks < 8; ++ks){
        bs_[ks] = *reinterpret_cast<const s8v*>(WsT + lr * 256 + ks * 32 + lk * 8);
        bt_[ks] = *reinterpret_cast<const s8v*>(WtT + lr * 256 + ks * 32 + lk * 8);
    }

    f4v accs = (f4v){0.f,0.f,0.f,0.f}, acct = (f4v){0.f,0.f,0.f,0.f};
    int row = min(r0 + lr, n - 1);
    const ushort* gsrow = Gs + (size_t)row * 256 + lk * 8;
    const ushort* gtrow = Gt + (size_t)row * 256 + lk * 8;
    #pragma unroll
    for (int ks = 0; ks < 8; ++ks){
        s8v a_s = *reinterpret_cast<const s8v*>(gsrow + ks * 32);
        s8v a_t = *reinterpret_cast<const s8v*>(gtrow + ks * 32);
        accs = __builtin_amdgcn_mfma_f32_16x16x32_bf16(a_s, bs_[ks], accs, 0, 0, 0);
        acct = __builtin_amdgcn_mfma_f32_16x16x32_bf16(a_t, bt_[ks], acct, 0, 0, 0);
    }
    #pragma unroll
    for (int j = 0; j < 4; ++j){
        int rr = r0 + lk * 4 + j;
        if (rr < n){
            unsigned pv = (unsigned)f2bf(accs[j]) | ((unsigned)f2bf(acct[j]) << 16);
            GSp[(size_t)rr * 16 + lr] = pv;
        }
    }
}

// ---------------- fused: SPMM-K + softmax (both branches) + cluster/con stats --------
__global__ __launch_bounds__(256) void spmm_k2_kernel(
        const unsigned* __restrict__ GSp,
        const int* __restrict__ roff, const uint2* __restrict__ csr,
        const float* __restrict__ bsv, const float* __restrict__ btv,
        float* __restrict__ asg, float* __restrict__ red, int n){
    int tid  = threadIdx.x;
    int wid  = tid >> 6, lane = tid & 63;
    int slot = lane >> 4, j = lane & 15;
    float bs_ = bsv[j], bt_ = btv[j];
    float cs_l = 0.f, con_l = 0.f;

    int rstride = gridDim.x * 4;
    for (int r = blockIdx.x * 4 + wid; r < n; r += rstride){
        int e0 = roff[r], e1 = roff[r + 1];
        float as_ = 0.f, at_ = 0.f;
        for (int e = e0 + slot; e < e1; e += 4){
            uint2 c = csr[e];
            float w = __uint_as_float(c.y);
            unsigned v = GSp[(size_t)c.x * 16 + j];
            as_ = fmaf(w, bflo(v), as_);
            at_ = fmaf(w, bfhi(v), at_);
        }
        as_ += __shfl_xor(as_, 16); as_ += __shfl_xor(as_, 32);
        at_ += __shfl_xor(at_, 16); at_ += __shfl_xor(at_, 32);
        float xs = selu1(as_ + bs_);
        float xt = selu1(at_ + bt_);
        float ms = xs, mt = xt;
        #pragma unroll
        for (int off = 8; off >= 1; off >>= 1){
            ms = fmaxf(ms, __shfl_xor(ms, off));
            mt = fmaxf(mt, __shfl_xor(mt, off));
        }
        float es = expf(xs - ms), et = expf(xt - mt);
        float ss = es, st = et;
        #pragma unroll
        for (int off = 8; off >= 1; off >>= 1){
            ss += __shfl_xor(ss, off);
            st += __shfl_xor(st, off);
        }
        float a = es / ss, b = et / st;
        if (slot == 0) asg[(size_t)r * 16 + j] = a;
        cs_l += a;
        float dot = a * b, na = a * a, nb = b * b;
        #pragma unroll
        for (int off = 8; off >= 1; off >>= 1){
            dot += __shfl_xor(dot, off);
            na  += __shfl_xor(na, off);
            nb  += __shfl_xor(nb, off);
        }
        if (j == 0){
            na = fmaxf(sqrtf(na), 1e-12f);
            nb = fmaxf(sqrtf(nb), 1e-12f);
            con_l += 2.f - 2.f * dot / (na * nb);
        }
    }

    // slots hold exact duplicates -> combine then scale by 1/4
    cs_l  += __shfl_xor(cs_l, 16);  cs_l  += __shfl_xor(cs_l, 32);  cs_l  *= 0.25f;
    con_l += __shfl_xor(con_l, 16); con_l += __shfl_xor(con_l, 32); con_l *= 0.25f;

    __shared__ float part[4][17];
    if (lane < 16) part[wid][lane] = cs_l;
    if (lane == 0) part[wid][16]   = con_l;
    __syncthreads();
    if (tid < 16){
        float s = part[0][tid] + part[1][tid] + part[2][tid] + part[3][tid];
        atomicAdd(&red[(16 + tid) * RSTRIDE], s);
    } else if (tid == 16){
        float s = part[0][16] + part[1][16] + part[2][16] + part[3][16];
        atomicAdd(&red[32 * RSTRIDE], s);
    }
}

// ---------------- per-edge: trace + nl[k] = sum_e S[dst_e][k] ----------------
__global__ __launch_bounds__(256) void edge_trace_kernel(const int* __restrict__ src,
        const int* __restrict__ dst, const float* __restrict__ as_,
        float* __restrict__ red, int E){
    int tid    = blockIdx.x * blockDim.x + threadIdx.x;
    int stride = gridDim.x * blockDim.x;
    float dot = 0.f;
    float nl[16] = {};
    for (int i = tid; i < E; i += stride){
        const float4* pa = reinterpret_cast<const float4*>(as_ + (size_t)src[i] * 16);
        const float4* pb = reinterpret_cast<const float4*>(as_ + (size_t)dst[i] * 16);
        #pragma unroll
        for (int q = 0; q < 4; ++q){
            float4 va = pa[q]; float4 vb = pb[q];
            dot = fmaf(va.x, vb.x, dot); dot = fmaf(va.y, vb.y, dot);
            dot = fmaf(va.z, vb.z, dot); dot = fmaf(va.w, vb.w, dot);
            nl[q*4+0] += vb.x; nl[q*4+1] += vb.y;
            nl[q*4+2] += vb.z; nl[q*4+3] += vb.w;
        }
    }
    #pragma unroll
    for (int off = 1; off < 64; off <<= 1){
        dot += __shfl_xor(dot, off);
        #pragma unroll
        for (int k = 0; k < 16; ++k) nl[k] += __shfl_xor(nl[k], off);
    }
    __shared__ float part[4][17];
    int wid = threadIdx.x >> 6, lane = threadIdx.x & 63;
    if (lane == 0){
        #pragma unroll
        for (int k = 0; k < 16; ++k) part[wid][k] = nl[k];
        part[wid][16] = dot;
    }
    __syncthreads();
    int t = threadIdx.x;
    if (t < 16){
        float s = part[0][t] + part[1][t] + part[2][t] + part[3][t];
        atomicAdd(&red[t * RSTRIDE], s);
    } else if (t == 16){
        float s = part[0][16] + part[1][16] + part[2][16] + part[3][16];
        atomicAdd(&red[33 * RSTRIDE], s);
    }
}

// ---------------- finalize ----------------
__global__ void finalize_kernel(const float* __restrict__ red, float* __restrict__ out,
                                int n, int E){
    float trace = red[33 * RSTRIDE];
    float nl2 = 0.f, cs2 = 0.f;
    #pragma unroll
    for (int k = 0; k < 16; ++k){
        nl2 = fmaf(red[k * RSTRIDE],        red[k * RSTRIDE],        nl2);
        cs2 = fmaf(red[(16 + k) * RSTRIDE], red[(16 + k) * RSTRIDE], cs2);
    }
    float twoE = 2.f * (float)E;
    float spectral = -(trace - nl2 / twoE) / twoE;
    float cluster  = sqrtf(cs2) / (float)n * 4.f - 1.f;
    float con      = red[32 * RSTRIDE] / (float)n;
    out[0] = spectral + cluster + con;
}

extern "C" void kernel_launch(void* const* d_in, const int* in_sizes, int n_in,
                              void* d_out, int out_size, void* d_ws, size_t ws_size,
                              hipStream_t stream){
    const int*   esrc = (const int*)d_in[0];
    const int*   edst = (const int*)d_in[1];
    const float* ew   = (const float*)d_in[2];
    const float* feat = (const float*)d_in[3];
    const float* faug = (const float*)d_in[4];
    const float* W1   = (const float*)d_in[5];
    const float* b1   = (const float*)d_in[6];
    const float* Wsm  = (const float*)d_in[7];
    const float* bsv  = (const float*)d_in[8];
    const float* Wtm  = (const float*)d_in[9];
    const float* btv  = (const float*)d_in[10];
    int E = in_sizes[0];
    int N = in_sizes[3] / Fdim;

    char* ws = (char*)d_ws;
    size_t off = 0;
    auto alloc = [&](size_t bytes) -> char* {
        char* p = ws + off;
        off = (off + bytes + 255) & ~(size_t)255;
        return p;
    };
    int nbuck = (N + 255) >> 8;
    unsigned char* XWp = (unsigned char*)alloc((size_t)N * 512);  // fp8 [N][512B]
    ushort*   Gs    = (ushort*)alloc((size_t)N * Hdim * 2);
    ushort*   Gt    = (ushort*)alloc((size_t)N * Hdim * 2);
    unsigned* GSp   = (unsigned*)alloc((size_t)N * Kc * 4);
    float*    ASG_S = (float*)alloc((size_t)N * Kc * 4);
    ushort*   WT    = (ushort*)alloc((size_t)256 * 256 * 2);
    ushort*   WsT   = (ushort*)alloc((size_t)16 * 256 * 2);
    ushort*   WtT   = (ushort*)alloc((size_t)16 * 256 * 2);
    int*      ROFF  = (int*)alloc((size_t)(N + 1) * 4);
    int*      BBASE = (int*)alloc((size_t)(nbuck + 1) * 4);
    int*      BCNT  = (int*)alloc((size_t)nbuck * 32 * 4);
    int*      BSRC  = (int*)alloc((size_t)nbuck * BCAP * 4);
    uint2*    BDW   = (uint2*)alloc((size_t)nbuck * BCAP * 8);
    uint2*    CSR8  = (uint2*)alloc((size_t)E * 8);
    float*    RED   = (float*)alloc((size_t)NRED * RSTRIDE * 4);

    hipMemsetAsync(BCNT, 0, (size_t)nbuck * 32 * 4, stream);
    hipMemsetAsync(RED, 0, (size_t)NRED * RSTRIDE * 4, stream);

    castw_kernel<<<dim3(16, 16), dim3(16, 16), 0, stream>>>(W1, WT);
    castwk_kernel<<<1, 256, 0, stream>>>(Wsm, Wtm, WsT, WtT);
    bin_kernel<<<256, 256, 0, stream>>>(esrc, edst, ew, BCNT, BSRC, BDW, E, nbuck);
    bbase_kernel<<<1, 256, 0, stream>>>(BCNT, BBASE, ROFF, nbuck, N);
    csr_build_kernel<<<nbuck, 256, 0, stream>>>(BCNT, BBASE, BSRC, BDW, ROFF, CSR8, N);

    dim3 gg(2, (N + 127) / 128, 2);
    gemm_xw_kernel<<<gg, 256, 0, stream>>>(feat, faug, WT, XWp, N);

    spmm_h2_kernel<<<(N + 3) / 4, 256, 0, stream>>>(XWp, ROFF, CSR8, b1, Gs, Gt, N);

    int nw = (N + 15) / 16;
    gemm_k2_kernel<<<(nw + 3) / 4, 256, 0, stream>>>(Gs, Gt, WsT, WtT, GSp, N);

    spmm_k2_kernel<<<2048, 256, 0, stream>>>(GSp, ROFF, CSR8, bsv, btv,
                                             ASG_S, RED, N);

    edge_trace_kernel<<<256, 256, 0, stream>>>(esrc, edst, ASG_S, RED, E);
    finalize_kernel<<<1, 1, 0, stream>>>(RED, (float*)d_out, N, E);
}